// Round 5
// baseline (1798.459 us; speedup 1.0000x reference)
//
#include <hip/hip_runtime.h>

#define B_ 8
#define N_ 4096
#define K_ 1024
#define NN_ 16
#define C1_ 128
#define C2_ 128
#define CIN_ 67
#define NROWS (B_*K_*NN_)   // 131072
#define NBLK  (NROWS/64)    // 2048 stats1 tiles
#define NBLK2 (NROWS/32)    // 4096 gemm2 tiles
#define BN_N 131072.0f

typedef unsigned short u16;

__device__ u16   g_knn[NROWS];
// BN accumulators, 8-way slot-spread (r18: 1M atomics on 256 addresses cost
// ~150 us of L2 same-address serialization; slot = blk&7 cuts it 8x).
__device__ float g_statsA[8*256];               // BN1 sum/sumsq per slot
__device__ float g_statsB[8*256];               // BN2 sum/sumsq per slot
__device__ float g_m2[B_*K_*C2_];
__device__ float g_W1T[68*128];                 // W1^T [q][o], row 67 zeroed
__device__ float g_W2T[128*128];                // W2^T [q][o]
__device__ __align__(16) float g_h1[(size_t)NROWS*128];   // pre-BN1 h1 (64 MB)

// --------------------------------------------------- DPP wave reduction ----
// Value-only max reduce-to-lane-63 (12 inst). Index resolved via ballot +
// ffs + readlane — exact for fps (blocked ascending per-lane index ranges).
template<int CTRL>
static __device__ __forceinline__ void dpp_maxv_step(float& v) {
    int vi = __float_as_int(v);
    int ov = __builtin_amdgcn_update_dpp(vi, vi, CTRL, 0xf, 0xf, false);
    v = fmaxf(v, __int_as_float(ov));
}
static __device__ __forceinline__ void wave_reduce_maxval(float& v) {
    dpp_maxv_step<0x111>(v);
    dpp_maxv_step<0x112>(v);
    dpp_maxv_step<0x114>(v);
    dpp_maxv_step<0x118>(v);
    dpp_maxv_step<0x142>(v);
    dpp_maxv_step<0x143>(v);   // lane 63 holds max
}
// kNN keeps the lexicographic pair reduce (its indices are interleaved).
template<int CTRL>
static __device__ __forceinline__ void dpp_min_step(float& v, int& ib) {
    int vi = __float_as_int(v);
    int ov = __builtin_amdgcn_update_dpp(vi, vi, CTRL, 0xf, 0xf, false);
    int oi = __builtin_amdgcn_update_dpp(ib, ib, CTRL, 0xf, 0xf, false);
    float of = __int_as_float(ov);
    if (of < v || (of == v && oi < ib)) { v = of; ib = oi; }
}
static __device__ __forceinline__ void wave_reduce_min(float& v, int& ib) {
    dpp_min_step<0x111>(v, ib);
    dpp_min_step<0x112>(v, ib);
    dpp_min_step<0x114>(v, ib);
    dpp_min_step<0x118>(v, ib);
    dpp_min_step<0x142>(v, ib);
    dpp_min_step<0x143>(v, ib);
}

// ------------------------------------- weight transpose + stats zeroing ----
__global__ void transpose_w_kernel(const float* __restrict__ W1,
                                   const float* __restrict__ W2) {
    int t = blockIdx.x * 256 + threadIdx.x;
    if (t < 8*256) { g_statsA[t] = 0.f; g_statsB[t] = 0.f; }
    if (t < 68*128) {
        int q = t >> 7, o = t & 127;
        g_W1T[t] = (q < CIN_) ? W1[o*CIN_ + q] : 0.f;
    }
    if (t < 128*128) {
        int q = t >> 7, o = t & 127;
        g_W2T[t] = W2[o*C1_ + q];
    }
}

// ---------------------------------------------------------------- FPS ------
// v13b: 2 batches per block (4 blocks, 512 thr, 8 waves), 8 pts/thread.
// The ~1100-cyc per-step tail (barrier arrival/wake + LDS latencies +
// reduce chain) is paid ONCE per paired step; the two batches' dist loops,
// reduces, and post-barrier select+gathers are independent -> overlap.
// v10/v11 lessons applied: register state loaded from LDS staging (not
// global -> no remat), NO global stores inside the step loop (sout in LDS,
// __syncthreads drains vmcnt(0)), per-thread state kept at 64 floats
// (~100 VGPR, no spill). Selection logic byte-identical to v9/v11
// (ascending lane index ranges, ballot lowest lane, strict-> cross-wave
// scan with waves ascending index) — verified passing in v9/v11/v12.
__global__ __launch_bounds__(512, 2) void fps_kernel(const float* __restrict__ xyz,
                                                     float* __restrict__ out_xyz) {
    __shared__ float sxA[N_*3];          // 48 KB batch A xyz
    __shared__ float sxB[N_*3];          // 48 KB batch B xyz
    __shared__ float soutA[K_*3];        // 12 KB selected centroids A
    __shared__ float soutB[K_*3];        // 12 KB selected centroids B
    __shared__ float wv[2][2][8];        // [parity][batch][wave]
    __shared__ int   wi[2][2][8];
    const int t = threadIdx.x;
    const int l = t & 63, w = t >> 6;    // 8 waves
    const int b0 = blockIdx.x * 2;
    const float* xbA = xyz + (size_t)b0       * (N_ * 3);
    const float* xbB = xyz + (size_t)(b0 + 1) * (N_ * 3);
    for (int e = t; e < N_*3; e += 512) { sxA[e] = xbA[e]; sxB[e] = xbB[e]; }
    __syncthreads();
    float xA[8], yA[8], zA[8], dA[8];
    float xB[8], yB[8], zB[8], dB[8];
    #pragma unroll
    for (int j = 0; j < 8; ++j) {
        int p = t * 8 + j;
        xA[j] = sxA[p*3+0]; yA[j] = sxA[p*3+1]; zA[j] = sxA[p*3+2];
        xB[j] = sxB[p*3+0]; yB[j] = sxB[p*3+1]; zB[j] = sxB[p*3+2];
        dA[j] = 1e10f; dB[j] = 1e10f;
    }
    int farA = 0, farB = 0;
    for (int s = 0; s < K_; ++s) {
        // uniform-address broadcast gathers; A and B independent -> overlap
        const float cxA = sxA[farA*3+0], cyA = sxA[farA*3+1], czA = sxA[farA*3+2];
        const float cxB = sxB[farB*3+0], cyB = sxB[farB*3+1], czB = sxB[farB*3+2];
        if (t == 0) { soutA[s*3+0] = cxA; soutA[s*3+1] = cyA; soutA[s*3+2] = czA; }
        if (t == 1) { soutB[s*3+0] = cxB; soutB[s*3+1] = cyB; soutB[s*3+2] = czB; }
        const int pb = s & 1;
        // ---- batch A local step ----
        {
            float v = -1.f; int ib = 0;
            {
                #pragma clang fp contract(fast)
                #pragma unroll
                for (int j = 0; j < 8; ++j) {
                    float dx = xA[j]-cxA, dy = yA[j]-cyA, dz = zA[j]-czA;
                    float dd = dx*dx + dy*dy + dz*dz;
                    dd = fminf(dA[j], dd);
                    dA[j] = dd;
                    if (dd > v) { v = dd; ib = t*8 + j; }   // ascending j: first max
                }
            }
            float vr = v;
            wave_reduce_maxval(vr);
            const float m = __int_as_float(__builtin_amdgcn_readlane(__float_as_int(vr), 63));
            unsigned long long mk = __ballot(v == m);
            const int ln  = __ffsll(mk) - 1;            // lowest tied lane
            const int wib = __builtin_amdgcn_readlane(ib, ln);
            if (l == 0) { wv[pb][0][w] = m; wi[pb][0][w] = wib; }
        }
        // ---- batch B local step ----
        {
            float v = -1.f; int ib = 0;
            {
                #pragma clang fp contract(fast)
                #pragma unroll
                for (int j = 0; j < 8; ++j) {
                    float dx = xB[j]-cxB, dy = yB[j]-cyB, dz = zB[j]-czB;
                    float dd = dx*dx + dy*dy + dz*dz;
                    dd = fminf(dB[j], dd);
                    dB[j] = dd;
                    if (dd > v) { v = dd; ib = t*8 + j; }
                }
            }
            float vr = v;
            wave_reduce_maxval(vr);
            const float m = __int_as_float(__builtin_amdgcn_readlane(__float_as_int(vr), 63));
            unsigned long long mk = __ballot(v == m);
            const int ln  = __ffsll(mk) - 1;
            const int wib = __builtin_amdgcn_readlane(ib, ln);
            if (l == 0) { wv[pb][1][w] = m; wi[pb][1][w] = wib; }
        }
        __syncthreads();                 // ONE barrier per paired step
        {
            float bv = wv[pb][0][0]; int bi = wi[pb][0][0];
            #pragma unroll
            for (int ww = 1; ww < 8; ++ww) {
                float ov = wv[pb][0][ww];
                if (ov > bv) { bv = ov; bi = wi[pb][0][ww]; }  // waves ascend idx
            }
            farA = bi & 4095;
        }
        {
            float bv = wv[pb][1][0]; int bi = wi[pb][1][0];
            #pragma unroll
            for (int ww = 1; ww < 8; ++ww) {
                float ov = wv[pb][1][ww];
                if (ov > bv) { bv = ov; bi = wi[pb][1][ww]; }
            }
            farB = bi & 4095;
        }
    }
    __syncthreads();                     // souts complete
    for (int e = t; e < K_*3; e += 512) {
        out_xyz[(size_t)b0*K_*3 + e]       = soutA[e];
        out_xyz[(size_t)(b0+1)*K_*3 + e]   = soutB[e];
    }
}

// ---------------------------------------------------------------- kNN ------
// Round-0 proven version: threshold-rescan selection (register-resident
// d[64], no writes after init -> no spill; poison variant spilled, r3).
__global__ __launch_bounds__(256) void knn_kernel(const float* __restrict__ xyz,
                                                  const float* __restrict__ newxyz) {
    __shared__ float px[N_], py[N_], pz[N_];
    const int b = blockIdx.y, t = threadIdx.x;
    const int l = t & 63, w = t >> 6;
    const int k = blockIdx.x * 4 + w;
    const int m = b*K_ + k;
    const float* xb = xyz + b * (N_ * 3);
    for (int p = t; p < N_; p += 256) {
        px[p] = xb[p*3+0]; py[p] = xb[p*3+1]; pz[p] = xb[p*3+2];
    }
    __syncthreads();
    const float cx = newxyz[m*3+0];
    const float cy = newxyz[m*3+1];
    const float cz = newxyz[m*3+2];
    float d[64];
    {
        #pragma clang fp contract(off)
        float sn = cx*cx; sn = sn + cy*cy; sn = sn + cz*cz;
        #pragma unroll
        for (int j = 0; j < 64; ++j) {
            int p = j*64 + l;
            float X = px[p], Y = py[p], Z = pz[p];
            float sp = X*X; sp = sp + Y*Y; sp = sp + Z*Z;
            float dt = cx*X; dt = dt + cy*Y; dt = dt + cz*Z;
            float t1 = sn + sp;
            d[j] = t1 - 2.0f*dt;
        }
    }
    float prevd = -1e38f; int previ = -1;
    for (int r = 0; r < NN_; ++r) {
        float bv = 1e38f; int bi = 0x7fffffff;
        #pragma unroll
        for (int j = 0; j < 64; ++j) {
            int p = j*64 + l;
            bool gt = (d[j] > prevd) || (d[j] == prevd && p > previ);
            bool lt = (d[j] < bv)   || (d[j] == bv   && p < bi);
            if (gt && lt) { bv = d[j]; bi = p; }
        }
        wave_reduce_min(bv, bi);
        previ = __builtin_amdgcn_readlane(bi, 63);
        prevd = __int_as_float(__builtin_amdgcn_readlane(__float_as_int(bv), 63));
        if (l == 0) g_knn[m*NN_ + r] = (u16)(previ & 4095);
    }
}

// ------------------------------------------------- GEMM1 + stats + h1 ------
__global__ __launch_bounds__(256) void stats1_kernel(
        const float* __restrict__ xyz, const float* __restrict__ points,
        const float* __restrict__ newxyz, const float* __restrict__ b1) {
    __shared__ union {
        float Xs[64][68];
        struct { float ps[16][128], pq[16][128]; } c;
    } u;
    __shared__ float cen[4][3];
    __shared__ int rowp[64];
    const int t = threadIdx.x;
    const int blk = blockIdx.x;
    const int b = blk >> 8;
    const int g0 = blk * 64;
    if (t < 64)  rowp[t] = ((int)g_knn[g0 + t]) & 4095;
    if (t < 12)  cen[t/3][t%3] = newxyz[(blk*4 + t/3)*3 + (t%3)];
    __syncthreads();
    for (int e = t; e < 64*68; e += 256) {
        int r = e / 68, c = e % 68;
        int p = rowp[r];
        float v = 0.f;
        if (c < 3)         v = xyz[(b*N_ + p)*3 + c] - cen[r >> 4][c];
        else if (c < CIN_) v = points[(b*N_ + p)*64 + (c - 3)];
        u.Xs[r][c] = v;
    }
    __syncthreads();
    const int rg = t >> 4, cg = t & 15;
    const int r0 = rg * 4;
    float acc[4][8];
    #pragma unroll
    for (int j = 0; j < 4; ++j)
        #pragma unroll
        for (int i = 0; i < 8; ++i) acc[j][i] = 0.f;
    for (int q4 = 0; q4 < 17; ++q4) {
        float4 xv[4];
        #pragma unroll
        for (int j = 0; j < 4; ++j) xv[j] = *(const float4*)&u.Xs[r0 + j][q4*4];
        #pragma unroll
        for (int i = 0; i < 8; ++i) {
            int o = cg + 16*i;
            float w0 = g_W1T[(q4*4+0)*128 + o];
            float w1 = g_W1T[(q4*4+1)*128 + o];
            float w2 = g_W1T[(q4*4+2)*128 + o];
            float w3 = g_W1T[(q4*4+3)*128 + o];
            #pragma unroll
            for (int j = 0; j < 4; ++j) {
                float a = acc[j][i];
                a = a + xv[j].x*w0; a = a + xv[j].y*w1;
                a = a + xv[j].z*w2; a = a + xv[j].w*w3;
                acc[j][i] = a;
            }
        }
    }
    __syncthreads();   // Xs reads done -> union reusable
    #pragma unroll
    for (int i = 0; i < 8; ++i) {
        int o = cg + 16*i;
        float bias = b1[o];
        float s = 0.f, sq = 0.f;
        #pragma unroll
        for (int j = 0; j < 4; ++j) {
            float v = acc[j][i] + bias;
            g_h1[(size_t)(g0 + r0 + j)*128 + o] = v;
            s += v; sq += v*v;
        }
        u.c.ps[rg][o] = s; u.c.pq[rg][o] = sq;
    }
    __syncthreads();
    if (t < 128) {
        float ts = 0.f, tq = 0.f;
        #pragma unroll
        for (int g = 0; g < 16; ++g) { ts += u.c.ps[g][t]; tq += u.c.pq[g][t]; }
        const int slot = (blk & 7) * 256;
        atomicAdd(&g_statsA[slot + t], ts);
        atomicAdd(&g_statsA[slot + 128 + t], tq);
    }
}

// ------------------------------------------------ BN1+ReLU + GEMM2 ---------
__global__ __launch_bounds__(256) void gemm2_kernel(
        const float* __restrict__ b2, const float* __restrict__ g1,
        const float* __restrict__ be1) {
    __shared__ float mn1[128], sc1[128], bb1[128];
    __shared__ union {
        float h1s[32][132];
        struct { float ps[16][128], pq[16][128], pm[16][128]; } c;
    } u;
    const int t = threadIdx.x;
    const int blk = blockIdx.x;
    const int g0 = blk * 32;
    if (t < 128) {
        float sum = 0.f, sq = 0.f;
        #pragma unroll
        for (int s = 0; s < 8; ++s) {
            sum += g_statsA[s*256 + t];
            sq  += g_statsA[s*256 + 128 + t];
        }
        float mean = sum * (1.f / BN_N);
        float var  = sq * (1.f / BN_N) - mean*mean;
        mn1[t] = mean; sc1[t] = (1.f / sqrtf(var + 1e-5f)) * g1[t];
        bb1[t] = be1[t];
    }
    __syncthreads();
    for (int e = t*4; e < 32*128; e += 1024) {
        float4 hv = *(const float4*)&g_h1[(size_t)g0*128 + e];
        int r = e >> 7, c = e & 127;
        u.h1s[r][c+0] = fmaxf((hv.x - mn1[c+0])*sc1[c+0] + bb1[c+0], 0.f);
        u.h1s[r][c+1] = fmaxf((hv.y - mn1[c+1])*sc1[c+1] + bb1[c+1], 0.f);
        u.h1s[r][c+2] = fmaxf((hv.z - mn1[c+2])*sc1[c+2] + bb1[c+2], 0.f);
        u.h1s[r][c+3] = fmaxf((hv.w - mn1[c+3])*sc1[c+3] + bb1[c+3], 0.f);
    }
    __syncthreads();
    const int rg = t >> 4, cg = t & 15;
    const int r0 = rg * 2;
    float acc2[2][8];
    #pragma unroll
    for (int j = 0; j < 2; ++j)
        #pragma unroll
        for (int i = 0; i < 8; ++i) acc2[j][i] = 0.f;
    for (int q4 = 0; q4 < 32; ++q4) {
        float4 xv0 = *(const float4*)&u.h1s[r0][q4*4];
        float4 xv1 = *(const float4*)&u.h1s[r0+1][q4*4];
        #pragma unroll
        for (int i = 0; i < 8; ++i) {
            int o = cg + 16*i;
            float w0 = g_W2T[(q4*4+0)*128 + o];
            float w1 = g_W2T[(q4*4+1)*128 + o];
            float w2 = g_W2T[(q4*4+2)*128 + o];
            float w3 = g_W2T[(q4*4+3)*128 + o];
            float a0 = acc2[0][i];
            a0 = a0 + xv0.x*w0; a0 = a0 + xv0.y*w1;
            a0 = a0 + xv0.z*w2; a0 = a0 + xv0.w*w3;
            acc2[0][i] = a0;
            float a1 = acc2[1][i];
            a1 = a1 + xv1.x*w0; a1 = a1 + xv1.y*w1;
            a1 = a1 + xv1.z*w2; a1 = a1 + xv1.w*w3;
            acc2[1][i] = a1;
        }
    }
    __syncthreads();   // h1s reads done -> union reusable
    #pragma unroll
    for (int i = 0; i < 8; ++i) {
        int o = cg + 16*i;
        float bias = b2[o];
        float s = 0.f, sq = 0.f, mx = -1e38f;
        #pragma unroll
        for (int j = 0; j < 2; ++j) {
            float v = acc2[j][i] + bias;
            s += v; sq += v*v; mx = fmaxf(mx, v);
        }
        u.c.ps[rg][o] = s; u.c.pq[rg][o] = sq; u.c.pm[rg][o] = mx;
    }
    __syncthreads();
    if (t < 128) {
        float ts = 0.f, tq = 0.f;
        #pragma unroll
        for (int g = 0; g < 16; ++g) { ts += u.c.ps[g][t]; tq += u.c.pq[g][t]; }
        const int slot = (blk & 7) * 256;
        atomicAdd(&g_statsB[slot + t], ts);
        atomicAdd(&g_statsB[slot + 128 + t], tq);
    }
    {
        const int o = t & 127, gg = t >> 7;
        float mx = u.c.pm[gg*8 + 0][o];
        #pragma unroll
        for (int g = 1; g < 8; ++g) mx = fmaxf(mx, u.c.pm[gg*8 + g][o]);
        g_m2[(blk*2 + gg)*128 + o] = mx;
    }
}

// ------------------------------------------------------------- finalize ----
__global__ __launch_bounds__(256) void final_kernel(
        const float* __restrict__ g2, const float* __restrict__ be2,
        float* __restrict__ outp) {
    __shared__ float mn[128], sc[128], bb[128];
    const int t = threadIdx.x;
    if (t < 128) {
        float sum = 0.f, sq = 0.f;
        #pragma unroll
        for (int s = 0; s < 8; ++s) {
            sum += g_statsB[s*256 + t];
            sq  += g_statsB[s*256 + 128 + t];
        }
        float mean = sum * (1.f / BN_N);
        float var  = sq * (1.f / BN_N) - mean*mean;
        float inv  = 1.f / sqrtf(var + 1e-5f);
        mn[t] = mean; sc[t] = inv * g2[t]; bb[t] = be2[t];
    }
    __syncthreads();
    const int m = blockIdx.x*2 + (t >> 7);
    const int c = t & 127;
    float v = (g_m2[m*128 + c] - mn[c]) * sc[c] + bb[c];
    v = fmaxf(v, 0.f);
    outp[m*C2_ + c] = v;
}

// -------------------------------------------------------------- launch -----
extern "C" void kernel_launch(void* const* d_in, const int* in_sizes, int n_in,
                              void* d_out, int out_size, void* d_ws, size_t ws_size,
                              hipStream_t stream) {
    const float* xyz    = (const float*)d_in[0];
    const float* points = (const float*)d_in[1];
    const float* W1     = (const float*)d_in[2];
    const float* b1     = (const float*)d_in[3];
    const float* g1     = (const float*)d_in[4];
    const float* be1    = (const float*)d_in[5];
    const float* W2     = (const float*)d_in[6];
    const float* b2     = (const float*)d_in[7];
    const float* g2     = (const float*)d_in[8];
    const float* be2    = (const float*)d_in[9];

    float* out_xyz = (float*)d_out;
    float* out_pts = (float*)d_out + B_*K_*3;

    (void)d_ws; (void)ws_size;

    transpose_w_kernel<<<64, 256, 0, stream>>>(W1, W2);   // + zeroes stats
    fps_kernel<<<B_/2, 512, 0, stream>>>(xyz, out_xyz);   // 2 batches/block
    knn_kernel<<<dim3(256, B_), 256, 0, stream>>>(xyz, out_xyz);
    stats1_kernel<<<NBLK, 256, 0, stream>>>(xyz, points, out_xyz, b1);
    gemm2_kernel<<<NBLK2, 256, 0, stream>>>(b2, g1, be1);
    final_kernel<<<B_*K_/2, 256, 0, stream>>>(g2, be2, out_pts);
}

// Round 6
// 1162.315 us; speedup vs baseline: 1.5473x; 1.5473x over previous
//
#include <hip/hip_runtime.h>

#define B_ 8
#define N_ 4096
#define K_ 1024
#define NN_ 16
#define C1_ 128
#define C2_ 128
#define CIN_ 67
#define NROWS (B_*K_*NN_)   // 131072
#define NBLK  (NROWS/64)    // 2048 stats1 tiles
#define NBLK2 (NROWS/32)    // 4096 gemm2 tiles
#define BN_N 131072.0f

typedef unsigned short u16;

__device__ u16   g_knn[NROWS];
// BN accumulators, 8-way slot-spread (r18: 1M atomics on 256 addresses cost
// ~150 us of L2 same-address serialization; slot = blk&7 cuts it 8x).
__device__ float g_statsA[8*256];               // BN1 sum/sumsq per slot
__device__ float g_statsB[8*256];               // BN2 sum/sumsq per slot
__device__ float g_m2[B_*K_*C2_];
__device__ float g_W1T[68*128];                 // W1^T [q][o], row 67 zeroed
__device__ float g_W2T[128*128];                // W2^T [q][o]
__device__ __align__(16) float g_h1[(size_t)NROWS*128];   // pre-BN1 h1 (64 MB)

// --------------------------------------------------- DPP wave reduction ----
// Value-only max reduce-to-lane-63 (12 inst). Index resolved via ballot +
// ffs + readlane — exact for fps (blocked ascending per-lane index ranges).
template<int CTRL>
static __device__ __forceinline__ void dpp_maxv_step(float& v) {
    int vi = __float_as_int(v);
    int ov = __builtin_amdgcn_update_dpp(vi, vi, CTRL, 0xf, 0xf, false);
    v = fmaxf(v, __int_as_float(ov));
}
static __device__ __forceinline__ void wave_reduce_maxval(float& v) {
    dpp_maxv_step<0x111>(v);
    dpp_maxv_step<0x112>(v);
    dpp_maxv_step<0x114>(v);
    dpp_maxv_step<0x118>(v);
    dpp_maxv_step<0x142>(v);
    dpp_maxv_step<0x143>(v);   // lane 63 holds max
}
// kNN keeps the lexicographic pair reduce (its indices are interleaved).
template<int CTRL>
static __device__ __forceinline__ void dpp_min_step(float& v, int& ib) {
    int vi = __float_as_int(v);
    int ov = __builtin_amdgcn_update_dpp(vi, vi, CTRL, 0xf, 0xf, false);
    int oi = __builtin_amdgcn_update_dpp(ib, ib, CTRL, 0xf, 0xf, false);
    float of = __int_as_float(ov);
    if (of < v || (of == v && oi < ib)) { v = of; ib = oi; }
}
static __device__ __forceinline__ void wave_reduce_min(float& v, int& ib) {
    dpp_min_step<0x111>(v, ib);
    dpp_min_step<0x112>(v, ib);
    dpp_min_step<0x114>(v, ib);
    dpp_min_step<0x118>(v, ib);
    dpp_min_step<0x142>(v, ib);
    dpp_min_step<0x143>(v, ib);
}

// ------------------------------------- weight transpose + stats zeroing ----
__global__ void transpose_w_kernel(const float* __restrict__ W1,
                                   const float* __restrict__ W2) {
    int t = blockIdx.x * 256 + threadIdx.x;
    if (t < 8*256) { g_statsA[t] = 0.f; g_statsB[t] = 0.f; }
    if (t < 68*128) {
        int q = t >> 7, o = t & 127;
        g_W1T[t] = (q < CIN_) ? W1[o*CIN_ + q] : 0.f;
    }
    if (t < 128*128) {
        int q = t >> 7, o = t & 127;
        g_W2T[t] = W2[o*C1_ + q];
    }
}

// ---------------------------------------------------------------- FPS ------
// v9 (r18, 609 us): value-only DPP max + ballot/ffs/readlane index; LDS sout
// buffer; one barrier/step. Selection == jnp.argmax (9 passing rounds).
// v10-v13 post-mortems: 2-batch pairing (any form) and coord-carrying
// payloads all regress — allocator won't keep >32 hot floats resident, and
// extra cndmasks on the dist loop cost more than the LDS gather they save.
// This structure is the session's proven optimum; do not restructure.
__global__ __launch_bounds__(256) void fps_kernel(const float* __restrict__ xyz,
                                                  float* __restrict__ out_xyz) {
    __shared__ float sx[N_*3];       // 48 KB xyz copy
    __shared__ float sout[K_*3];     // 12 KB selected centroids
    __shared__ float wv[2][4];
    __shared__ int   wi[2][4];
    const int b = blockIdx.x, t = threadIdx.x;
    const int l = t & 63, w = t >> 6;
    const float* xb = xyz + b * (N_ * 3);
    for (int e = t; e < N_*3; e += 256) sx[e] = xb[e];
    __syncthreads();
    float x0[16], y0[16], z0[16], dist[16];
    #pragma unroll
    for (int j = 0; j < 16; ++j) {
        int p = t * 16 + j;
        x0[j] = sx[p*3+0]; y0[j] = sx[p*3+1]; z0[j] = sx[p*3+2];
        dist[j] = 1e10f;
    }
    int far = 0;
    for (int s = 0; s < K_; ++s) {
        const float cx = sx[far*3+0], cy = sx[far*3+1], cz = sx[far*3+2];
        if (t == 0) {
            sout[s*3+0] = cx; sout[s*3+1] = cy; sout[s*3+2] = cz;
        }
        float v = -1.f; int ib = 0;
        {
            #pragma clang fp contract(fast)
            #pragma unroll
            for (int j = 0; j < 16; ++j) {
                float dx = x0[j]-cx, dy = y0[j]-cy, dz = z0[j]-cz;
                float dd = dx*dx + dy*dy + dz*dz;
                dd = fminf(dist[j], dd);
                dist[j] = dd;
                if (dd > v) { v = dd; ib = t*16 + j; }   // ascending j: first max
            }
        }
        float vr = v;
        wave_reduce_maxval(vr);
        const float m = __int_as_float(__builtin_amdgcn_readlane(__float_as_int(vr), 63));
        unsigned long long mk = __ballot(v == m);
        const int ln  = __ffsll((unsigned long long)mk) - 1;   // lowest tied lane
        const int wib = __builtin_amdgcn_readlane(ib, ln);
        const int pb = s & 1;
        if (l == 0) { wv[pb][w] = m; wi[pb][w] = wib; }
        __syncthreads();                   // only barrier per step
        float bv = wv[pb][0]; int bi = wi[pb][0];
        #pragma unroll
        for (int ww = 1; ww < 4; ++ww) {
            float ov = wv[pb][ww];
            if (ov > bv) { bv = ov; bi = wi[pb][ww]; }   // waves ascend idx
        }
        far = bi & 4095;
    }
    __syncthreads();                       // sout complete
    for (int e = t; e < K_*3; e += 256) out_xyz[b*K_*3 + e] = sout[e];
}

// ---------------------------------------------------------------- kNN ------
// v2: 8 centers per block (512 thr, 8 waves) sharing one 48 KB staging ->
// 3 blocks/CU = 24 waves/CU (was 12). Pure TLP doubling for latency hiding;
// per-wave selection code identical to the r0-proven threshold-rescan
// (poison variant spilled, r3 — do not revisit).
__global__ __launch_bounds__(512) void knn_kernel(const float* __restrict__ xyz,
                                                  const float* __restrict__ newxyz) {
    __shared__ float px[N_], py[N_], pz[N_];
    const int b = blockIdx.y, t = threadIdx.x;
    const int l = t & 63, w = t >> 6;      // 8 waves
    const int k = blockIdx.x * 8 + w;
    const int m = b*K_ + k;
    const float* xb = xyz + b * (N_ * 3);
    for (int p = t; p < N_; p += 512) {
        px[p] = xb[p*3+0]; py[p] = xb[p*3+1]; pz[p] = xb[p*3+2];
    }
    __syncthreads();
    const float cx = newxyz[m*3+0];
    const float cy = newxyz[m*3+1];
    const float cz = newxyz[m*3+2];
    float d[64];
    {
        #pragma clang fp contract(off)
        float sn = cx*cx; sn = sn + cy*cy; sn = sn + cz*cz;
        #pragma unroll
        for (int j = 0; j < 64; ++j) {
            int p = j*64 + l;
            float X = px[p], Y = py[p], Z = pz[p];
            float sp = X*X; sp = sp + Y*Y; sp = sp + Z*Z;
            float dt = cx*X; dt = dt + cy*Y; dt = dt + cz*Z;
            float t1 = sn + sp;
            d[j] = t1 - 2.0f*dt;
        }
    }
    float prevd = -1e38f; int previ = -1;
    for (int r = 0; r < NN_; ++r) {
        float bv = 1e38f; int bi = 0x7fffffff;
        #pragma unroll
        for (int j = 0; j < 64; ++j) {
            int p = j*64 + l;
            bool gt = (d[j] > prevd) || (d[j] == prevd && p > previ);
            bool lt = (d[j] < bv)   || (d[j] == bv   && p < bi);
            if (gt && lt) { bv = d[j]; bi = p; }
        }
        wave_reduce_min(bv, bi);
        previ = __builtin_amdgcn_readlane(bi, 63);
        prevd = __int_as_float(__builtin_amdgcn_readlane(__float_as_int(bv), 63));
        if (l == 0) g_knn[m*NN_ + r] = (u16)(previ & 4095);
    }
}

// ------------------------------------------------- GEMM1 + stats + h1 ------
__global__ __launch_bounds__(256) void stats1_kernel(
        const float* __restrict__ xyz, const float* __restrict__ points,
        const float* __restrict__ newxyz, const float* __restrict__ b1) {
    __shared__ union {
        float Xs[64][68];
        struct { float ps[16][128], pq[16][128]; } c;
    } u;
    __shared__ float cen[4][3];
    __shared__ int rowp[64];
    const int t = threadIdx.x;
    const int blk = blockIdx.x;
    const int b = blk >> 8;
    const int g0 = blk * 64;
    if (t < 64)  rowp[t] = ((int)g_knn[g0 + t]) & 4095;
    if (t < 12)  cen[t/3][t%3] = newxyz[(blk*4 + t/3)*3 + (t%3)];
    __syncthreads();
    for (int e = t; e < 64*68; e += 256) {
        int r = e / 68, c = e % 68;
        int p = rowp[r];
        float v = 0.f;
        if (c < 3)         v = xyz[(b*N_ + p)*3 + c] - cen[r >> 4][c];
        else if (c < CIN_) v = points[(b*N_ + p)*64 + (c - 3)];
        u.Xs[r][c] = v;
    }
    __syncthreads();
    const int rg = t >> 4, cg = t & 15;
    const int r0 = rg * 4;
    float acc[4][8];
    #pragma unroll
    for (int j = 0; j < 4; ++j)
        #pragma unroll
        for (int i = 0; i < 8; ++i) acc[j][i] = 0.f;
    for (int q4 = 0; q4 < 17; ++q4) {
        float4 xv[4];
        #pragma unroll
        for (int j = 0; j < 4; ++j) xv[j] = *(const float4*)&u.Xs[r0 + j][q4*4];
        #pragma unroll
        for (int i = 0; i < 8; ++i) {
            int o = cg + 16*i;
            float w0 = g_W1T[(q4*4+0)*128 + o];
            float w1 = g_W1T[(q4*4+1)*128 + o];
            float w2 = g_W1T[(q4*4+2)*128 + o];
            float w3 = g_W1T[(q4*4+3)*128 + o];
            #pragma unroll
            for (int j = 0; j < 4; ++j) {
                float a = acc[j][i];
                a = a + xv[j].x*w0; a = a + xv[j].y*w1;
                a = a + xv[j].z*w2; a = a + xv[j].w*w3;
                acc[j][i] = a;
            }
        }
    }
    __syncthreads();   // Xs reads done -> union reusable
    #pragma unroll
    for (int i = 0; i < 8; ++i) {
        int o = cg + 16*i;
        float bias = b1[o];
        float s = 0.f, sq = 0.f;
        #pragma unroll
        for (int j = 0; j < 4; ++j) {
            float v = acc[j][i] + bias;
            g_h1[(size_t)(g0 + r0 + j)*128 + o] = v;
            s += v; sq += v*v;
        }
        u.c.ps[rg][o] = s; u.c.pq[rg][o] = sq;
    }
    __syncthreads();
    if (t < 128) {
        float ts = 0.f, tq = 0.f;
        #pragma unroll
        for (int g = 0; g < 16; ++g) { ts += u.c.ps[g][t]; tq += u.c.pq[g][t]; }
        const int slot = (blk & 7) * 256;
        atomicAdd(&g_statsA[slot + t], ts);
        atomicAdd(&g_statsA[slot + 128 + t], tq);
    }
}

// ------------------------------------------------ BN1+ReLU + GEMM2 ---------
__global__ __launch_bounds__(256) void gemm2_kernel(
        const float* __restrict__ b2, const float* __restrict__ g1,
        const float* __restrict__ be1) {
    __shared__ float mn1[128], sc1[128], bb1[128];
    __shared__ union {
        float h1s[32][132];
        struct { float ps[16][128], pq[16][128], pm[16][128]; } c;
    } u;
    const int t = threadIdx.x;
    const int blk = blockIdx.x;
    const int g0 = blk * 32;
    if (t < 128) {
        float sum = 0.f, sq = 0.f;
        #pragma unroll
        for (int s = 0; s < 8; ++s) {
            sum += g_statsA[s*256 + t];
            sq  += g_statsA[s*256 + 128 + t];
        }
        float mean = sum * (1.f / BN_N);
        float var  = sq * (1.f / BN_N) - mean*mean;
        mn1[t] = mean; sc1[t] = (1.f / sqrtf(var + 1e-5f)) * g1[t];
        bb1[t] = be1[t];
    }
    __syncthreads();
    for (int e = t*4; e < 32*128; e += 1024) {
        float4 hv = *(const float4*)&g_h1[(size_t)g0*128 + e];
        int r = e >> 7, c = e & 127;
        u.h1s[r][c+0] = fmaxf((hv.x - mn1[c+0])*sc1[c+0] + bb1[c+0], 0.f);
        u.h1s[r][c+1] = fmaxf((hv.y - mn1[c+1])*sc1[c+1] + bb1[c+1], 0.f);
        u.h1s[r][c+2] = fmaxf((hv.z - mn1[c+2])*sc1[c+2] + bb1[c+2], 0.f);
        u.h1s[r][c+3] = fmaxf((hv.w - mn1[c+3])*sc1[c+3] + bb1[c+3], 0.f);
    }
    __syncthreads();
    const int rg = t >> 4, cg = t & 15;
    const int r0 = rg * 2;
    float acc2[2][8];
    #pragma unroll
    for (int j = 0; j < 2; ++j)
        #pragma unroll
        for (int i = 0; i < 8; ++i) acc2[j][i] = 0.f;
    for (int q4 = 0; q4 < 32; ++q4) {
        float4 xv0 = *(const float4*)&u.h1s[r0][q4*4];
        float4 xv1 = *(const float4*)&u.h1s[r0+1][q4*4];
        #pragma unroll
        for (int i = 0; i < 8; ++i) {
            int o = cg + 16*i;
            float w0 = g_W2T[(q4*4+0)*128 + o];
            float w1 = g_W2T[(q4*4+1)*128 + o];
            float w2 = g_W2T[(q4*4+2)*128 + o];
            float w3 = g_W2T[(q4*4+3)*128 + o];
            float a0 = acc2[0][i];
            a0 = a0 + xv0.x*w0; a0 = a0 + xv0.y*w1;
            a0 = a0 + xv0.z*w2; a0 = a0 + xv0.w*w3;
            acc2[0][i] = a0;
            float a1 = acc2[1][i];
            a1 = a1 + xv1.x*w0; a1 = a1 + xv1.y*w1;
            a1 = a1 + xv1.z*w2; a1 = a1 + xv1.w*w3;
            acc2[1][i] = a1;
        }
    }
    __syncthreads();   // h1s reads done -> union reusable
    #pragma unroll
    for (int i = 0; i < 8; ++i) {
        int o = cg + 16*i;
        float bias = b2[o];
        float s = 0.f, sq = 0.f, mx = -1e38f;
        #pragma unroll
        for (int j = 0; j < 2; ++j) {
            float v = acc2[j][i] + bias;
            s += v; sq += v*v; mx = fmaxf(mx, v);
        }
        u.c.ps[rg][o] = s; u.c.pq[rg][o] = sq; u.c.pm[rg][o] = mx;
    }
    __syncthreads();
    if (t < 128) {
        float ts = 0.f, tq = 0.f;
        #pragma unroll
        for (int g = 0; g < 16; ++g) { ts += u.c.ps[g][t]; tq += u.c.pq[g][t]; }
        const int slot = (blk & 7) * 256;
        atomicAdd(&g_statsB[slot + t], ts);
        atomicAdd(&g_statsB[slot + 128 + t], tq);
    }
    {
        const int o = t & 127, gg = t >> 7;
        float mx = u.c.pm[gg*8 + 0][o];
        #pragma unroll
        for (int g = 1; g < 8; ++g) mx = fmaxf(mx, u.c.pm[gg*8 + g][o]);
        g_m2[(blk*2 + gg)*128 + o] = mx;
    }
}

// ------------------------------------------------------------- finalize ----
__global__ __launch_bounds__(256) void final_kernel(
        const float* __restrict__ g2, const float* __restrict__ be2,
        float* __restrict__ outp) {
    __shared__ float mn[128], sc[128], bb[128];
    const int t = threadIdx.x;
    if (t < 128) {
        float sum = 0.f, sq = 0.f;
        #pragma unroll
        for (int s = 0; s < 8; ++s) {
            sum += g_statsB[s*256 + t];
            sq  += g_statsB[s*256 + 128 + t];
        }
        float mean = sum * (1.f / BN_N);
        float var  = sq * (1.f / BN_N) - mean*mean;
        float inv  = 1.f / sqrtf(var + 1e-5f);
        mn[t] = mean; sc[t] = inv * g2[t]; bb[t] = be2[t];
    }
    __syncthreads();
    const int m = blockIdx.x*2 + (t >> 7);
    const int c = t & 127;
    float v = (g_m2[m*128 + c] - mn[c]) * sc[c] + bb[c];
    v = fmaxf(v, 0.f);
    outp[m*C2_ + c] = v;
}

// -------------------------------------------------------------- launch -----
extern "C" void kernel_launch(void* const* d_in, const int* in_sizes, int n_in,
                              void* d_out, int out_size, void* d_ws, size_t ws_size,
                              hipStream_t stream) {
    const float* xyz    = (const float*)d_in[0];
    const float* points = (const float*)d_in[1];
    const float* W1     = (const float*)d_in[2];
    const float* b1     = (const float*)d_in[3];
    const float* g1     = (const float*)d_in[4];
    const float* be1    = (const float*)d_in[5];
    const float* W2     = (const float*)d_in[6];
    const float* b2     = (const float*)d_in[7];
    const float* g2     = (const float*)d_in[8];
    const float* be2    = (const float*)d_in[9];

    float* out_xyz = (float*)d_out;
    float* out_pts = (float*)d_out + B_*K_*3;

    (void)d_ws; (void)ws_size;

    transpose_w_kernel<<<64, 256, 0, stream>>>(W1, W2);   // + zeroes stats
    fps_kernel<<<B_, 256, 0, stream>>>(xyz, out_xyz);
    knn_kernel<<<dim3(128, B_), 512, 0, stream>>>(xyz, out_xyz);  // 8 ctr/blk
    stats1_kernel<<<NBLK, 256, 0, stream>>>(xyz, points, out_xyz, b1);
    gemm2_kernel<<<NBLK2, 256, 0, stream>>>(b2, g1, be1);
    final_kernel<<<B_*K_/2, 256, 0, stream>>>(g2, be2, out_pts);
}

// Round 7
// 1052.262 us; speedup vs baseline: 1.7091x; 1.1046x over previous
//
#include <hip/hip_runtime.h>

#define B_ 8
#define N_ 4096
#define K_ 1024
#define NN_ 16
#define C1_ 128
#define C2_ 128
#define CIN_ 67
#define NROWS (B_*K_*NN_)   // 131072
#define NBLK  (NROWS/64)    // 2048 stats1 tiles
#define NBLK2 (NROWS/64)    // 2048 gemm2 tiles (64-row retile)
#define BN_N 131072.0f

typedef unsigned short u16;

__device__ u16   g_knn[NROWS];
// BN accumulators, 8-way slot-spread (r18: 1M atomics on 256 addresses cost
// ~150 us of L2 same-address serialization; slot = blk&7 cuts it 8x).
__device__ float g_statsA[8*256];               // BN1 sum/sumsq per slot
__device__ float g_statsB[8*256];               // BN2 sum/sumsq per slot
__device__ float g_m2[B_*K_*C2_];
__device__ float g_W1T[68*128];                 // W1^T [q][o], row 67 zeroed
__device__ float g_W2T[128*128];                // W2^T [q][o]
__device__ __align__(16) float g_h1[(size_t)NROWS*128];   // pre-BN1 h1 (64 MB)

// --------------------------------------------------- DPP wave reduction ----
// Value-only max reduce-to-lane-63 (12 inst). Index resolved via ballot +
// ffs + readlane — exact for fps (blocked ascending per-lane index ranges).
template<int CTRL>
static __device__ __forceinline__ void dpp_maxv_step(float& v) {
    int vi = __float_as_int(v);
    int ov = __builtin_amdgcn_update_dpp(vi, vi, CTRL, 0xf, 0xf, false);
    v = fmaxf(v, __int_as_float(ov));
}
static __device__ __forceinline__ void wave_reduce_maxval(float& v) {
    dpp_maxv_step<0x111>(v);
    dpp_maxv_step<0x112>(v);
    dpp_maxv_step<0x114>(v);
    dpp_maxv_step<0x118>(v);
    dpp_maxv_step<0x142>(v);
    dpp_maxv_step<0x143>(v);   // lane 63 holds max
}
// kNN keeps the lexicographic pair reduce (its indices are interleaved).
template<int CTRL>
static __device__ __forceinline__ void dpp_min_step(float& v, int& ib) {
    int vi = __float_as_int(v);
    int ov = __builtin_amdgcn_update_dpp(vi, vi, CTRL, 0xf, 0xf, false);
    int oi = __builtin_amdgcn_update_dpp(ib, ib, CTRL, 0xf, 0xf, false);
    float of = __int_as_float(ov);
    if (of < v || (of == v && oi < ib)) { v = of; ib = oi; }
}
static __device__ __forceinline__ void wave_reduce_min(float& v, int& ib) {
    dpp_min_step<0x111>(v, ib);
    dpp_min_step<0x112>(v, ib);
    dpp_min_step<0x114>(v, ib);
    dpp_min_step<0x118>(v, ib);
    dpp_min_step<0x142>(v, ib);
    dpp_min_step<0x143>(v, ib);
}

// ------------------------------------- weight transpose + stats zeroing ----
__global__ void transpose_w_kernel(const float* __restrict__ W1,
                                   const float* __restrict__ W2) {
    int t = blockIdx.x * 256 + threadIdx.x;
    if (t < 8*256) { g_statsA[t] = 0.f; g_statsB[t] = 0.f; }
    if (t < 68*128) {
        int q = t >> 7, o = t & 127;
        g_W1T[t] = (q < CIN_) ? W1[o*CIN_ + q] : 0.f;
    }
    if (t < 128*128) {
        int q = t >> 7, o = t & 127;
        g_W2T[t] = W2[o*C1_ + q];
    }
}

// ---------------------------------------------------------------- FPS ------
// v9 (r18, 609 us): value-only DPP max + ballot/ffs/readlane index; LDS sout
// buffer; one barrier/step. Selection == jnp.argmax (9 passing rounds).
// v10-v13 post-mortems: 2-batch pairing (any form) and coord-carrying
// payloads all regress — allocator won't keep >32 hot floats resident, and
// extra cndmasks on the dist loop cost more than the LDS gather they save.
// This structure is the session's proven optimum; do not restructure.
__global__ __launch_bounds__(256) void fps_kernel(const float* __restrict__ xyz,
                                                  float* __restrict__ out_xyz) {
    __shared__ float sx[N_*3];       // 48 KB xyz copy
    __shared__ float sout[K_*3];     // 12 KB selected centroids
    __shared__ float wv[2][4];
    __shared__ int   wi[2][4];
    const int b = blockIdx.x, t = threadIdx.x;
    const int l = t & 63, w = t >> 6;
    const float* xb = xyz + b * (N_ * 3);
    for (int e = t; e < N_*3; e += 256) sx[e] = xb[e];
    __syncthreads();
    float x0[16], y0[16], z0[16], dist[16];
    #pragma unroll
    for (int j = 0; j < 16; ++j) {
        int p = t * 16 + j;
        x0[j] = sx[p*3+0]; y0[j] = sx[p*3+1]; z0[j] = sx[p*3+2];
        dist[j] = 1e10f;
    }
    int far = 0;
    for (int s = 0; s < K_; ++s) {
        const float cx = sx[far*3+0], cy = sx[far*3+1], cz = sx[far*3+2];
        if (t == 0) {
            sout[s*3+0] = cx; sout[s*3+1] = cy; sout[s*3+2] = cz;
        }
        float v = -1.f; int ib = 0;
        {
            #pragma clang fp contract(fast)
            #pragma unroll
            for (int j = 0; j < 16; ++j) {
                float dx = x0[j]-cx, dy = y0[j]-cy, dz = z0[j]-cz;
                float dd = dx*dx + dy*dy + dz*dz;
                dd = fminf(dist[j], dd);
                dist[j] = dd;
                if (dd > v) { v = dd; ib = t*16 + j; }   // ascending j: first max
            }
        }
        float vr = v;
        wave_reduce_maxval(vr);
        const float m = __int_as_float(__builtin_amdgcn_readlane(__float_as_int(vr), 63));
        unsigned long long mk = __ballot(v == m);
        const int ln  = __ffsll((unsigned long long)mk) - 1;   // lowest tied lane
        const int wib = __builtin_amdgcn_readlane(ib, ln);
        const int pb = s & 1;
        if (l == 0) { wv[pb][w] = m; wi[pb][w] = wib; }
        __syncthreads();                   // only barrier per step
        float bv = wv[pb][0]; int bi = wi[pb][0];
        #pragma unroll
        for (int ww = 1; ww < 4; ++ww) {
            float ov = wv[pb][ww];
            if (ov > bv) { bv = ov; bi = wi[pb][ww]; }   // waves ascend idx
        }
        far = bi & 4095;
    }
    __syncthreads();                       // sout complete
    for (int e = t; e < K_*3; e += 256) out_xyz[b*K_*3 + e] = sout[e];
}

// ---------------------------------------------------------------- kNN ------
// r0-proven version (4 centers/block, 256 thr). r6 showed 8-wave TLP
// doubling REGRESSES (+54 us): selection loop is VALU-issue-bound, extra
// waves only queue on the issue port. Poison variant spilled (r3).
__global__ __launch_bounds__(256) void knn_kernel(const float* __restrict__ xyz,
                                                  const float* __restrict__ newxyz) {
    __shared__ float px[N_], py[N_], pz[N_];
    const int b = blockIdx.y, t = threadIdx.x;
    const int l = t & 63, w = t >> 6;
    const int k = blockIdx.x * 4 + w;
    const int m = b*K_ + k;
    const float* xb = xyz + b * (N_ * 3);
    for (int p = t; p < N_; p += 256) {
        px[p] = xb[p*3+0]; py[p] = xb[p*3+1]; pz[p] = xb[p*3+2];
    }
    __syncthreads();
    const float cx = newxyz[m*3+0];
    const float cy = newxyz[m*3+1];
    const float cz = newxyz[m*3+2];
    float d[64];
    {
        #pragma clang fp contract(off)
        float sn = cx*cx; sn = sn + cy*cy; sn = sn + cz*cz;
        #pragma unroll
        for (int j = 0; j < 64; ++j) {
            int p = j*64 + l;
            float X = px[p], Y = py[p], Z = pz[p];
            float sp = X*X; sp = sp + Y*Y; sp = sp + Z*Z;
            float dt = cx*X; dt = dt + cy*Y; dt = dt + cz*Z;
            float t1 = sn + sp;
            d[j] = t1 - 2.0f*dt;
        }
    }
    float prevd = -1e38f; int previ = -1;
    for (int r = 0; r < NN_; ++r) {
        float bv = 1e38f; int bi = 0x7fffffff;
        #pragma unroll
        for (int j = 0; j < 64; ++j) {
            int p = j*64 + l;
            bool gt = (d[j] > prevd) || (d[j] == prevd && p > previ);
            bool lt = (d[j] < bv)   || (d[j] == bv   && p < bi);
            if (gt && lt) { bv = d[j]; bi = p; }
        }
        wave_reduce_min(bv, bi);
        previ = __builtin_amdgcn_readlane(bi, 63);
        prevd = __int_as_float(__builtin_amdgcn_readlane(__float_as_int(bv), 63));
        if (l == 0) g_knn[m*NN_ + r] = (u16)(previ & 4095);
    }
}

// ------------------------------------------------- GEMM1 + stats + h1 ------
__global__ __launch_bounds__(256) void stats1_kernel(
        const float* __restrict__ xyz, const float* __restrict__ points,
        const float* __restrict__ newxyz, const float* __restrict__ b1) {
    __shared__ union {
        float Xs[64][68];
        struct { float ps[16][128], pq[16][128]; } c;
    } u;
    __shared__ float cen[4][3];
    __shared__ int rowp[64];
    const int t = threadIdx.x;
    const int blk = blockIdx.x;
    const int b = blk >> 8;
    const int g0 = blk * 64;
    if (t < 64)  rowp[t] = ((int)g_knn[g0 + t]) & 4095;
    if (t < 12)  cen[t/3][t%3] = newxyz[(blk*4 + t/3)*3 + (t%3)];
    __syncthreads();
    for (int e = t; e < 64*68; e += 256) {
        int r = e / 68, c = e % 68;
        int p = rowp[r];
        float v = 0.f;
        if (c < 3)         v = xyz[(b*N_ + p)*3 + c] - cen[r >> 4][c];
        else if (c < CIN_) v = points[(b*N_ + p)*64 + (c - 3)];
        u.Xs[r][c] = v;
    }
    __syncthreads();
    const int rg = t >> 4, cg = t & 15;
    const int r0 = rg * 4;
    float acc[4][8];
    #pragma unroll
    for (int j = 0; j < 4; ++j)
        #pragma unroll
        for (int i = 0; i < 8; ++i) acc[j][i] = 0.f;
    for (int q4 = 0; q4 < 17; ++q4) {
        float4 xv[4];
        #pragma unroll
        for (int j = 0; j < 4; ++j) xv[j] = *(const float4*)&u.Xs[r0 + j][q4*4];
        #pragma unroll
        for (int i = 0; i < 8; ++i) {
            int o = cg + 16*i;
            float w0 = g_W1T[(q4*4+0)*128 + o];
            float w1 = g_W1T[(q4*4+1)*128 + o];
            float w2 = g_W1T[(q4*4+2)*128 + o];
            float w3 = g_W1T[(q4*4+3)*128 + o];
            #pragma unroll
            for (int j = 0; j < 4; ++j) {
                float a = acc[j][i];
                a = a + xv[j].x*w0; a = a + xv[j].y*w1;
                a = a + xv[j].z*w2; a = a + xv[j].w*w3;
                acc[j][i] = a;
            }
        }
    }
    __syncthreads();   // Xs reads done -> union reusable
    #pragma unroll
    for (int i = 0; i < 8; ++i) {
        int o = cg + 16*i;
        float bias = b1[o];
        float s = 0.f, sq = 0.f;
        #pragma unroll
        for (int j = 0; j < 4; ++j) {
            float v = acc[j][i] + bias;
            g_h1[(size_t)(g0 + r0 + j)*128 + o] = v;
            s += v; sq += v*v;
        }
        u.c.ps[rg][o] = s; u.c.pq[rg][o] = sq;
    }
    __syncthreads();
    if (t < 128) {
        float ts = 0.f, tq = 0.f;
        #pragma unroll
        for (int g = 0; g < 16; ++g) { ts += u.c.ps[g][t]; tq += u.c.pq[g][t]; }
        const int slot = (blk & 7) * 256;
        atomicAdd(&g_statsA[slot + t], ts);
        atomicAdd(&g_statsA[slot + 128 + t], tq);
    }
}

// ------------------------------------------------ BN1+ReLU + GEMM2 ---------
// r7 retile: 64 rows/block (2048 blocks), 4 rows/thread — stats1's proven
// shape. Weight-load instructions halve (32 loads feed 128 FMA, was 64),
// per-thread ILP doubles, statsB atomics halve. LDS 35 KB -> 4 blocks/CU.
__global__ __launch_bounds__(256) void gemm2_kernel(
        const float* __restrict__ b2, const float* __restrict__ g1,
        const float* __restrict__ be1) {
    __shared__ float mn1[128], sc1[128], bb1[128];
    __shared__ union {
        float h1s[64][132];
        struct { float ps[16][128], pq[16][128], pm[16][128]; } c;
    } u;
    const int t = threadIdx.x;
    const int blk = blockIdx.x;
    const int g0 = blk * 64;
    if (t < 128) {
        float sum = 0.f, sq = 0.f;
        #pragma unroll
        for (int s = 0; s < 8; ++s) {
            sum += g_statsA[s*256 + t];
            sq  += g_statsA[s*256 + 128 + t];
        }
        float mean = sum * (1.f / BN_N);
        float var  = sq * (1.f / BN_N) - mean*mean;
        mn1[t] = mean; sc1[t] = (1.f / sqrtf(var + 1e-5f)) * g1[t];
        bb1[t] = be1[t];
    }
    __syncthreads();
    for (int e = t*4; e < 64*128; e += 1024) {
        float4 hv = *(const float4*)&g_h1[(size_t)g0*128 + e];
        int r = e >> 7, c = e & 127;
        u.h1s[r][c+0] = fmaxf((hv.x - mn1[c+0])*sc1[c+0] + bb1[c+0], 0.f);
        u.h1s[r][c+1] = fmaxf((hv.y - mn1[c+1])*sc1[c+1] + bb1[c+1], 0.f);
        u.h1s[r][c+2] = fmaxf((hv.z - mn1[c+2])*sc1[c+2] + bb1[c+2], 0.f);
        u.h1s[r][c+3] = fmaxf((hv.w - mn1[c+3])*sc1[c+3] + bb1[c+3], 0.f);
    }
    __syncthreads();
    const int rg = t >> 4, cg = t & 15;
    const int r0 = rg * 4;
    float acc2[4][8];
    #pragma unroll
    for (int j = 0; j < 4; ++j)
        #pragma unroll
        for (int i = 0; i < 8; ++i) acc2[j][i] = 0.f;
    for (int q4 = 0; q4 < 32; ++q4) {
        float4 xv[4];
        #pragma unroll
        for (int j = 0; j < 4; ++j) xv[j] = *(const float4*)&u.h1s[r0 + j][q4*4];
        #pragma unroll
        for (int i = 0; i < 8; ++i) {
            int o = cg + 16*i;
            float w0 = g_W2T[(q4*4+0)*128 + o];
            float w1 = g_W2T[(q4*4+1)*128 + o];
            float w2 = g_W2T[(q4*4+2)*128 + o];
            float w3 = g_W2T[(q4*4+3)*128 + o];
            #pragma unroll
            for (int j = 0; j < 4; ++j) {
                float a = acc2[j][i];
                a = a + xv[j].x*w0; a = a + xv[j].y*w1;
                a = a + xv[j].z*w2; a = a + xv[j].w*w3;
                acc2[j][i] = a;
            }
        }
    }
    __syncthreads();   // h1s reads done -> union reusable
    #pragma unroll
    for (int i = 0; i < 8; ++i) {
        int o = cg + 16*i;
        float bias = b2[o];
        float s = 0.f, sq = 0.f, mx = -1e38f;
        #pragma unroll
        for (int j = 0; j < 4; ++j) {
            float v = acc2[j][i] + bias;
            s += v; sq += v*v; mx = fmaxf(mx, v);
        }
        u.c.ps[rg][o] = s; u.c.pq[rg][o] = sq; u.c.pm[rg][o] = mx;
    }
    __syncthreads();
    if (t < 128) {
        float ts = 0.f, tq = 0.f;
        #pragma unroll
        for (int g = 0; g < 16; ++g) { ts += u.c.ps[g][t]; tq += u.c.pq[g][t]; }
        const int slot = (blk & 7) * 256;
        atomicAdd(&g_statsB[slot + t], ts);
        atomicAdd(&g_statsB[slot + 128 + t], tq);
    }
    {
        // max-pool: 4 output rows (16 input rows = 4 rg's each)
        const int o = t & 127, gg = t >> 7;          // gg in {0,1}
        #pragma unroll
        for (int h = 0; h < 2; ++h) {
            const int gm = h*2 + gg;                 // 0..3
            float mx = u.c.pm[gm*4 + 0][o];
            #pragma unroll
            for (int g = 1; g < 4; ++g) mx = fmaxf(mx, u.c.pm[gm*4 + g][o]);
            g_m2[(blk*4 + gm)*128 + o] = mx;
        }
    }
}

// ------------------------------------------------------------- finalize ----
__global__ __launch_bounds__(256) void final_kernel(
        const float* __restrict__ g2, const float* __restrict__ be2,
        float* __restrict__ outp) {
    __shared__ float mn[128], sc[128], bb[128];
    const int t = threadIdx.x;
    if (t < 128) {
        float sum = 0.f, sq = 0.f;
        #pragma unroll
        for (int s = 0; s < 8; ++s) {
            sum += g_statsB[s*256 + t];
            sq  += g_statsB[s*256 + 128 + t];
        }
        float mean = sum * (1.f / BN_N);
        float var  = sq * (1.f / BN_N) - mean*mean;
        float inv  = 1.f / sqrtf(var + 1e-5f);
        mn[t] = mean; sc[t] = inv * g2[t]; bb[t] = be2[t];
    }
    __syncthreads();
    const int m = blockIdx.x*2 + (t >> 7);
    const int c = t & 127;
    float v = (g_m2[m*128 + c] - mn[c]) * sc[c] + bb[c];
    v = fmaxf(v, 0.f);
    outp[m*C2_ + c] = v;
}

// -------------------------------------------------------------- launch -----
extern "C" void kernel_launch(void* const* d_in, const int* in_sizes, int n_in,
                              void* d_out, int out_size, void* d_ws, size_t ws_size,
                              hipStream_t stream) {
    const float* xyz    = (const float*)d_in[0];
    const float* points = (const float*)d_in[1];
    const float* W1     = (const float*)d_in[2];
    const float* b1     = (const float*)d_in[3];
    const float* g1     = (const float*)d_in[4];
    const float* be1    = (const float*)d_in[5];
    const float* W2     = (const float*)d_in[6];
    const float* b2     = (const float*)d_in[7];
    const float* g2     = (const float*)d_in[8];
    const float* be2    = (const float*)d_in[9];

    float* out_xyz = (float*)d_out;
    float* out_pts = (float*)d_out + B_*K_*3;

    (void)d_ws; (void)ws_size;

    transpose_w_kernel<<<64, 256, 0, stream>>>(W1, W2);   // + zeroes stats
    fps_kernel<<<B_, 256, 0, stream>>>(xyz, out_xyz);
    knn_kernel<<<dim3(256, B_), 256, 0, stream>>>(xyz, out_xyz);
    stats1_kernel<<<NBLK, 256, 0, stream>>>(xyz, points, out_xyz, b1);
    gemm2_kernel<<<NBLK2, 256, 0, stream>>>(b2, g1, be1);
    final_kernel<<<B_*K_/2, 256, 0, stream>>>(g2, be2, out_pts);
}

// Round 8
// 1015.060 us; speedup vs baseline: 1.7718x; 1.0367x over previous
//
#include <hip/hip_runtime.h>

#define B_ 8
#define N_ 4096
#define K_ 1024
#define NN_ 16
#define C1_ 128
#define C2_ 128
#define CIN_ 67
#define NROWS (B_*K_*NN_)   // 131072
#define NBLK  (NROWS/64)    // 2048 stats1 tiles
#define NBLK2 (NROWS/128)   // 1024 gemm2 tiles (128-row retile)
#define BN_N 131072.0f

typedef unsigned short u16;

__device__ u16   g_knn[NROWS];
// BN accumulators, 8-way slot-spread (r18: 1M atomics on 256 addresses cost
// ~150 us of L2 same-address serialization; slot = blk&7 cuts it 8x).
__device__ float g_statsA[8*256];               // BN1 sum/sumsq per slot
__device__ float g_statsB[8*256];               // BN2 sum/sumsq per slot
__device__ float g_m2[B_*K_*C2_];
__device__ float g_W1T[68*128];                 // W1^T [q][o], row 67 zeroed
__device__ float g_W2T[128*128];                // W2^T [q][o]
__device__ __align__(16) float g_h1[(size_t)NROWS*128];   // pre-BN1 h1 (64 MB)

// --------------------------------------------------- DPP wave reduction ----
// Value-only max reduce-to-lane-63 (12 inst). Index resolved via ballot +
// ffs + readlane — exact for fps (blocked ascending per-lane index ranges).
template<int CTRL>
static __device__ __forceinline__ void dpp_maxv_step(float& v) {
    int vi = __float_as_int(v);
    int ov = __builtin_amdgcn_update_dpp(vi, vi, CTRL, 0xf, 0xf, false);
    v = fmaxf(v, __int_as_float(ov));
}
static __device__ __forceinline__ void wave_reduce_maxval(float& v) {
    dpp_maxv_step<0x111>(v);
    dpp_maxv_step<0x112>(v);
    dpp_maxv_step<0x114>(v);
    dpp_maxv_step<0x118>(v);
    dpp_maxv_step<0x142>(v);
    dpp_maxv_step<0x143>(v);   // lane 63 holds max
}
// kNN keeps the lexicographic pair reduce (its indices are interleaved).
template<int CTRL>
static __device__ __forceinline__ void dpp_min_step(float& v, int& ib) {
    int vi = __float_as_int(v);
    int ov = __builtin_amdgcn_update_dpp(vi, vi, CTRL, 0xf, 0xf, false);
    int oi = __builtin_amdgcn_update_dpp(ib, ib, CTRL, 0xf, 0xf, false);
    float of = __int_as_float(ov);
    if (of < v || (of == v && oi < ib)) { v = of; ib = oi; }
}
static __device__ __forceinline__ void wave_reduce_min(float& v, int& ib) {
    dpp_min_step<0x111>(v, ib);
    dpp_min_step<0x112>(v, ib);
    dpp_min_step<0x114>(v, ib);
    dpp_min_step<0x118>(v, ib);
    dpp_min_step<0x142>(v, ib);
    dpp_min_step<0x143>(v, ib);
}

// ------------------------------------- weight transpose + stats zeroing ----
__global__ void transpose_w_kernel(const float* __restrict__ W1,
                                   const float* __restrict__ W2) {
    int t = blockIdx.x * 256 + threadIdx.x;
    if (t < 8*256) { g_statsA[t] = 0.f; g_statsB[t] = 0.f; }
    if (t < 68*128) {
        int q = t >> 7, o = t & 127;
        g_W1T[t] = (q < CIN_) ? W1[o*CIN_ + q] : 0.f;
    }
    if (t < 128*128) {
        int q = t >> 7, o = t & 127;
        g_W2T[t] = W2[o*C1_ + q];
    }
}

// ---------------------------------------------------------------- FPS ------
// v9 (r18, 609 us): value-only DPP max + ballot/ffs/readlane index; LDS sout
// buffer; one barrier/step. Selection == jnp.argmax (9 passing rounds).
// v10-v13 post-mortems: 2-batch pairing (any form) and coord-carrying
// payloads all regress — allocator won't keep >32 hot floats resident, and
// extra cndmasks on the dist loop cost more than the LDS gather they save.
// This structure is the session's proven optimum; do not restructure.
__global__ __launch_bounds__(256) void fps_kernel(const float* __restrict__ xyz,
                                                  float* __restrict__ out_xyz) {
    __shared__ float sx[N_*3];       // 48 KB xyz copy
    __shared__ float sout[K_*3];     // 12 KB selected centroids
    __shared__ float wv[2][4];
    __shared__ int   wi[2][4];
    const int b = blockIdx.x, t = threadIdx.x;
    const int l = t & 63, w = t >> 6;
    const float* xb = xyz + b * (N_ * 3);
    for (int e = t; e < N_*3; e += 256) sx[e] = xb[e];
    __syncthreads();
    float x0[16], y0[16], z0[16], dist[16];
    #pragma unroll
    for (int j = 0; j < 16; ++j) {
        int p = t * 16 + j;
        x0[j] = sx[p*3+0]; y0[j] = sx[p*3+1]; z0[j] = sx[p*3+2];
        dist[j] = 1e10f;
    }
    int far = 0;
    for (int s = 0; s < K_; ++s) {
        const float cx = sx[far*3+0], cy = sx[far*3+1], cz = sx[far*3+2];
        if (t == 0) {
            sout[s*3+0] = cx; sout[s*3+1] = cy; sout[s*3+2] = cz;
        }
        float v = -1.f; int ib = 0;
        {
            #pragma clang fp contract(fast)
            #pragma unroll
            for (int j = 0; j < 16; ++j) {
                float dx = x0[j]-cx, dy = y0[j]-cy, dz = z0[j]-cz;
                float dd = dx*dx + dy*dy + dz*dz;
                dd = fminf(dist[j], dd);
                dist[j] = dd;
                if (dd > v) { v = dd; ib = t*16 + j; }   // ascending j: first max
            }
        }
        float vr = v;
        wave_reduce_maxval(vr);
        const float m = __int_as_float(__builtin_amdgcn_readlane(__float_as_int(vr), 63));
        unsigned long long mk = __ballot(v == m);
        const int ln  = __ffsll((unsigned long long)mk) - 1;   // lowest tied lane
        const int wib = __builtin_amdgcn_readlane(ib, ln);
        const int pb = s & 1;
        if (l == 0) { wv[pb][w] = m; wi[pb][w] = wib; }
        __syncthreads();                   // only barrier per step
        float bv = wv[pb][0]; int bi = wi[pb][0];
        #pragma unroll
        for (int ww = 1; ww < 4; ++ww) {
            float ov = wv[pb][ww];
            if (ov > bv) { bv = ov; bi = wi[pb][ww]; }   // waves ascend idx
        }
        far = bi & 4095;
    }
    __syncthreads();                       // sout complete
    for (int e = t; e < K_*3; e += 256) out_xyz[b*K_*3 + e] = sout[e];
}

// ---------------------------------------------------------------- kNN ------
// Poison-select (r3-verified correct; its "spill" was a misread first-
// iteration cold-TLB artifact — steady-state arithmetic showed −30 us vs
// threshold-rescan). Plain lexicographic min (7 inst/iter vs 14), then
// branchless poison of the winner. Successive stable minima == top_k order.
// r6: knn is VALU-issue-bound — do NOT add waves; shrink instructions.
__global__ __launch_bounds__(256) void knn_kernel(const float* __restrict__ xyz,
                                                  const float* __restrict__ newxyz) {
    __shared__ float px[N_], py[N_], pz[N_];
    const int b = blockIdx.y, t = threadIdx.x;
    const int l = t & 63, w = t >> 6;
    const int k = blockIdx.x * 4 + w;
    const int m = b*K_ + k;
    const float* xb = xyz + b * (N_ * 3);
    for (int p = t; p < N_; p += 256) {
        px[p] = xb[p*3+0]; py[p] = xb[p*3+1]; pz[p] = xb[p*3+2];
    }
    __syncthreads();
    const float cx = newxyz[m*3+0];
    const float cy = newxyz[m*3+1];
    const float cz = newxyz[m*3+2];
    float d[64];
    {
        #pragma clang fp contract(off)
        float sn = cx*cx; sn = sn + cy*cy; sn = sn + cz*cz;
        #pragma unroll
        for (int j = 0; j < 64; ++j) {
            int p = j*64 + l;
            float X = px[p], Y = py[p], Z = pz[p];
            float sp = X*X; sp = sp + Y*Y; sp = sp + Z*Z;
            float dt = cx*X; dt = dt + cy*Y; dt = dt + cz*Z;
            float t1 = sn + sp;
            d[j] = t1 - 2.0f*dt;
        }
    }
    for (int r = 0; r < NN_; ++r) {
        float bv = 1e38f; int bi = 0x7fffffff;
        #pragma unroll
        for (int j = 0; j < 64; ++j) {
            int p = j*64 + l;
            bool lt = (d[j] < bv) || (d[j] == bv && p < bi);
            if (lt) { bv = d[j]; bi = p; }
        }
        wave_reduce_min(bv, bi);
        const int win = __builtin_amdgcn_readlane(bi, 63);
        if (l == 0) g_knn[m*NN_ + r] = (u16)(win & 4095);
        #pragma unroll
        for (int j = 0; j < 64; ++j) {
            int p = j*64 + l;
            d[j] = (p == win) ? 1e38f : d[j];     // poison winner
        }
    }
}

// ------------------------------------------------- GEMM1 + stats + h1 ------
__global__ __launch_bounds__(256) void stats1_kernel(
        const float* __restrict__ xyz, const float* __restrict__ points,
        const float* __restrict__ newxyz, const float* __restrict__ b1) {
    __shared__ union {
        float Xs[64][68];
        struct { float ps[16][128], pq[16][128]; } c;
    } u;
    __shared__ float cen[4][3];
    __shared__ int rowp[64];
    const int t = threadIdx.x;
    const int blk = blockIdx.x;
    const int b = blk >> 8;
    const int g0 = blk * 64;
    if (t < 64)  rowp[t] = ((int)g_knn[g0 + t]) & 4095;
    if (t < 12)  cen[t/3][t%3] = newxyz[(blk*4 + t/3)*3 + (t%3)];
    __syncthreads();
    for (int e = t; e < 64*68; e += 256) {
        int r = e / 68, c = e % 68;
        int p = rowp[r];
        float v = 0.f;
        if (c < 3)         v = xyz[(b*N_ + p)*3 + c] - cen[r >> 4][c];
        else if (c < CIN_) v = points[(b*N_ + p)*64 + (c - 3)];
        u.Xs[r][c] = v;
    }
    __syncthreads();
    const int rg = t >> 4, cg = t & 15;
    const int r0 = rg * 4;
    float acc[4][8];
    #pragma unroll
    for (int j = 0; j < 4; ++j)
        #pragma unroll
        for (int i = 0; i < 8; ++i) acc[j][i] = 0.f;
    for (int q4 = 0; q4 < 17; ++q4) {
        float4 xv[4];
        #pragma unroll
        for (int j = 0; j < 4; ++j) xv[j] = *(const float4*)&u.Xs[r0 + j][q4*4];
        #pragma unroll
        for (int i = 0; i < 8; ++i) {
            int o = cg + 16*i;
            float w0 = g_W1T[(q4*4+0)*128 + o];
            float w1 = g_W1T[(q4*4+1)*128 + o];
            float w2 = g_W1T[(q4*4+2)*128 + o];
            float w3 = g_W1T[(q4*4+3)*128 + o];
            #pragma unroll
            for (int j = 0; j < 4; ++j) {
                float a = acc[j][i];
                a = a + xv[j].x*w0; a = a + xv[j].y*w1;
                a = a + xv[j].z*w2; a = a + xv[j].w*w3;
                acc[j][i] = a;
            }
        }
    }
    __syncthreads();   // Xs reads done -> union reusable
    #pragma unroll
    for (int i = 0; i < 8; ++i) {
        int o = cg + 16*i;
        float bias = b1[o];
        float s = 0.f, sq = 0.f;
        #pragma unroll
        for (int j = 0; j < 4; ++j) {
            float v = acc[j][i] + bias;
            g_h1[(size_t)(g0 + r0 + j)*128 + o] = v;
            s += v; sq += v*v;
        }
        u.c.ps[rg][o] = s; u.c.pq[rg][o] = sq;
    }
    __syncthreads();
    if (t < 128) {
        float ts = 0.f, tq = 0.f;
        #pragma unroll
        for (int g = 0; g < 16; ++g) { ts += u.c.ps[g][t]; tq += u.c.pq[g][t]; }
        const int slot = (blk & 7) * 256;
        atomicAdd(&g_statsA[slot + t], ts);
        atomicAdd(&g_statsA[slot + 128 + t], tq);
    }
}

// ------------------------------------------------ BN1+ReLU + GEMM2 ---------
// r8 retile: 128 rows/block (1024 blocks), 8 rows/thread. Second application
// of the r7-proven lever: weight loads per FMA halve again (32 loads feed
// 256 FMA), statsB atomics halve, LDS 68 KB -> 2 blocks/CU (8 waves/CU).
__global__ __launch_bounds__(256) void gemm2_kernel(
        const float* __restrict__ b2, const float* __restrict__ g1,
        const float* __restrict__ be1) {
    __shared__ float mn1[128], sc1[128], bb1[128];
    __shared__ union {
        float h1s[128][132];
        struct { float ps[16][128], pq[16][128], pm[16][128]; } c;
    } u;
    const int t = threadIdx.x;
    const int blk = blockIdx.x;
    const int g0 = blk * 128;
    if (t < 128) {
        float sum = 0.f, sq = 0.f;
        #pragma unroll
        for (int s = 0; s < 8; ++s) {
            sum += g_statsA[s*256 + t];
            sq  += g_statsA[s*256 + 128 + t];
        }
        float mean = sum * (1.f / BN_N);
        float var  = sq * (1.f / BN_N) - mean*mean;
        mn1[t] = mean; sc1[t] = (1.f / sqrtf(var + 1e-5f)) * g1[t];
        bb1[t] = be1[t];
    }
    __syncthreads();
    for (int e = t*4; e < 128*128; e += 1024) {
        float4 hv = *(const float4*)&g_h1[(size_t)g0*128 + e];
        int r = e >> 7, c = e & 127;
        u.h1s[r][c+0] = fmaxf((hv.x - mn1[c+0])*sc1[c+0] + bb1[c+0], 0.f);
        u.h1s[r][c+1] = fmaxf((hv.y - mn1[c+1])*sc1[c+1] + bb1[c+1], 0.f);
        u.h1s[r][c+2] = fmaxf((hv.z - mn1[c+2])*sc1[c+2] + bb1[c+2], 0.f);
        u.h1s[r][c+3] = fmaxf((hv.w - mn1[c+3])*sc1[c+3] + bb1[c+3], 0.f);
    }
    __syncthreads();
    const int rg = t >> 4, cg = t & 15;
    const int r0 = rg * 8;
    float acc2[8][8];
    #pragma unroll
    for (int j = 0; j < 8; ++j)
        #pragma unroll
        for (int i = 0; i < 8; ++i) acc2[j][i] = 0.f;
    for (int q4 = 0; q4 < 32; ++q4) {
        float4 xv[8];
        #pragma unroll
        for (int j = 0; j < 8; ++j) xv[j] = *(const float4*)&u.h1s[r0 + j][q4*4];
        #pragma unroll
        for (int i = 0; i < 8; ++i) {
            int o = cg + 16*i;
            float w0 = g_W2T[(q4*4+0)*128 + o];
            float w1 = g_W2T[(q4*4+1)*128 + o];
            float w2 = g_W2T[(q4*4+2)*128 + o];
            float w3 = g_W2T[(q4*4+3)*128 + o];
            #pragma unroll
            for (int j = 0; j < 8; ++j) {
                float a = acc2[j][i];
                a = a + xv[j].x*w0; a = a + xv[j].y*w1;
                a = a + xv[j].z*w2; a = a + xv[j].w*w3;
                acc2[j][i] = a;
            }
        }
    }
    __syncthreads();   // h1s reads done -> union reusable
    #pragma unroll
    for (int i = 0; i < 8; ++i) {
        int o = cg + 16*i;
        float bias = b2[o];
        float s = 0.f, sq = 0.f, mx = -1e38f;
        #pragma unroll
        for (int j = 0; j < 8; ++j) {
            float v = acc2[j][i] + bias;
            s += v; sq += v*v; mx = fmaxf(mx, v);
        }
        u.c.ps[rg][o] = s; u.c.pq[rg][o] = sq; u.c.pm[rg][o] = mx;
    }
    __syncthreads();
    if (t < 128) {
        float ts = 0.f, tq = 0.f;
        #pragma unroll
        for (int g = 0; g < 16; ++g) { ts += u.c.ps[g][t]; tq += u.c.pq[g][t]; }
        const int slot = (blk & 7) * 256;
        atomicAdd(&g_statsB[slot + t], ts);
        atomicAdd(&g_statsB[slot + 128 + t], tq);
    }
    {
        // max-pool: 128 rows = 8 output m-rows (16 input rows each);
        // pm[rg] covers rows rg*8..rg*8+7 -> m-row gm uses rg = 2gm, 2gm+1.
        const int o = t & 127, gg = t >> 7;          // gg in {0,1}
        #pragma unroll
        for (int h = 0; h < 4; ++h) {
            const int gm = h*2 + gg;                 // 0..7
            float mx = fmaxf(u.c.pm[gm*2 + 0][o], u.c.pm[gm*2 + 1][o]);
            g_m2[(blk*8 + gm)*128 + o] = mx;
        }
    }
}

// ------------------------------------------------------------- finalize ----
__global__ __launch_bounds__(256) void final_kernel(
        const float* __restrict__ g2, const float* __restrict__ be2,
        float* __restrict__ outp) {
    __shared__ float mn[128], sc[128], bb[128];
    const int t = threadIdx.x;
    if (t < 128) {
        float sum = 0.f, sq = 0.f;
        #pragma unroll
        for (int s = 0; s < 8; ++s) {
            sum += g_statsB[s*256 + t];
            sq  += g_statsB[s*256 + 128 + t];
        }
        float mean = sum * (1.f / BN_N);
        float var  = sq * (1.f / BN_N) - mean*mean;
        float inv  = 1.f / sqrtf(var + 1e-5f);
        mn[t] = mean; sc[t] = inv * g2[t]; bb[t] = be2[t];
    }
    __syncthreads();
    const int m = blockIdx.x*2 + (t >> 7);
    const int c = t & 127;
    float v = (g_m2[m*128 + c] - mn[c]) * sc[c] + bb[c];
    v = fmaxf(v, 0.f);
    outp[m*C2_ + c] = v;
}

// -------------------------------------------------------------- launch -----
extern "C" void kernel_launch(void* const* d_in, const int* in_sizes, int n_in,
                              void* d_out, int out_size, void* d_ws, size_t ws_size,
                              hipStream_t stream) {
    const float* xyz    = (const float*)d_in[0];
    const float* points = (const float*)d_in[1];
    const float* W1     = (const float*)d_in[2];
    const float* b1     = (const float*)d_in[3];
    const float* g1     = (const float*)d_in[4];
    const float* be1    = (const float*)d_in[5];
    const float* W2     = (const float*)d_in[6];
    const float* b2     = (const float*)d_in[7];
    const float* g2     = (const float*)d_in[8];
    const float* be2    = (const float*)d_in[9];

    float* out_xyz = (float*)d_out;
    float* out_pts = (float*)d_out + B_*K_*3;

    (void)d_ws; (void)ws_size;

    transpose_w_kernel<<<64, 256, 0, stream>>>(W1, W2);   // + zeroes stats
    fps_kernel<<<B_, 256, 0, stream>>>(xyz, out_xyz);
    knn_kernel<<<dim3(256, B_), 256, 0, stream>>>(xyz, out_xyz);
    stats1_kernel<<<NBLK, 256, 0, stream>>>(xyz, points, out_xyz, b1);
    gemm2_kernel<<<NBLK2, 256, 0, stream>>>(b2, g1, be1);
    final_kernel<<<B_*K_/2, 256, 0, stream>>>(g2, be2, out_pts);
}

// Round 9
// 1003.167 us; speedup vs baseline: 1.7928x; 1.0119x over previous
//
#include <hip/hip_runtime.h>

#define B_ 8
#define N_ 4096
#define K_ 1024
#define NN_ 16
#define C1_ 128
#define C2_ 128
#define CIN_ 67
#define NROWS (B_*K_*NN_)   // 131072
#define NBLK  (NROWS/64)    // 2048 stats1 tiles
#define NBLK2 (NROWS/128)   // 1024 gemm2 tiles (128-row retile)
#define BN_N 131072.0f

typedef unsigned short u16;

__device__ u16   g_knn[NROWS];
// BN accumulators, 8-way slot-spread (r18: 1M atomics on 256 addresses cost
// ~150 us of L2 same-address serialization; slot = blk&7 cuts it 8x).
__device__ float g_statsA[8*256];               // BN1 sum/sumsq per slot
__device__ float g_statsB[8*256];               // BN2 sum/sumsq per slot
__device__ float g_m2[B_*K_*C2_];
// W1^T PERMUTED row order: q<64 -> points channel 3+q; q 64..66 -> xyz
// channel q-64; q=67 -> 0. Matches stats1's Xs layout (points 0-63,
// xyz 64-66, zero 67) so staging is float4/b128 aligned.
__device__ float g_W1T[68*128];
__device__ float g_W2T[128*128];                // W2^T [q][o]
__device__ __align__(16) float g_h1[(size_t)NROWS*128];   // pre-BN1 h1 (64 MB)

// --------------------------------------------------- DPP wave reduction ----
// Value-only max reduce-to-lane-63 (12 inst). Index resolved via ballot +
// ffs + readlane — exact for fps (blocked ascending per-lane index ranges).
template<int CTRL>
static __device__ __forceinline__ void dpp_maxv_step(float& v) {
    int vi = __float_as_int(v);
    int ov = __builtin_amdgcn_update_dpp(vi, vi, CTRL, 0xf, 0xf, false);
    v = fmaxf(v, __int_as_float(ov));
}
static __device__ __forceinline__ void wave_reduce_maxval(float& v) {
    dpp_maxv_step<0x111>(v);
    dpp_maxv_step<0x112>(v);
    dpp_maxv_step<0x114>(v);
    dpp_maxv_step<0x118>(v);
    dpp_maxv_step<0x142>(v);
    dpp_maxv_step<0x143>(v);   // lane 63 holds max
}
// kNN keeps the lexicographic pair reduce (its indices are interleaved).
template<int CTRL>
static __device__ __forceinline__ void dpp_min_step(float& v, int& ib) {
    int vi = __float_as_int(v);
    int ov = __builtin_amdgcn_update_dpp(vi, vi, CTRL, 0xf, 0xf, false);
    int oi = __builtin_amdgcn_update_dpp(ib, ib, CTRL, 0xf, 0xf, false);
    float of = __int_as_float(ov);
    if (of < v || (of == v && oi < ib)) { v = of; ib = oi; }
}
static __device__ __forceinline__ void wave_reduce_min(float& v, int& ib) {
    dpp_min_step<0x111>(v, ib);
    dpp_min_step<0x112>(v, ib);
    dpp_min_step<0x114>(v, ib);
    dpp_min_step<0x118>(v, ib);
    dpp_min_step<0x142>(v, ib);
    dpp_min_step<0x143>(v, ib);
}

// ------------------------------------- weight transpose + stats zeroing ----
__global__ void transpose_w_kernel(const float* __restrict__ W1,
                                   const float* __restrict__ W2) {
    int t = blockIdx.x * 256 + threadIdx.x;
    if (t < 8*256) { g_statsA[t] = 0.f; g_statsB[t] = 0.f; }
    if (t < 68*128) {
        int q = t >> 7, o = t & 127;
        float v;
        if (q < 64)      v = W1[o*CIN_ + 3 + q];      // points channels
        else if (q < 67) v = W1[o*CIN_ + (q - 64)];   // xyz channels
        else             v = 0.f;
        g_W1T[t] = v;
    }
    if (t < 128*128) {
        int q = t >> 7, o = t & 127;
        g_W2T[t] = W2[o*C1_ + q];
    }
}

// ---------------------------------------------------------------- FPS ------
// v9 (r18, 609 us): value-only DPP max + ballot/ffs/readlane index; LDS sout
// buffer; one barrier/step. Selection == jnp.argmax (9 passing rounds).
// v10-v13 post-mortems: 2-batch pairing (any form) and coord-carrying
// payloads all regress — allocator won't keep >32 hot floats resident, and
// extra cndmasks on the dist loop cost more than the LDS gather they save.
// This structure is the session's proven optimum; do not restructure.
__global__ __launch_bounds__(256) void fps_kernel(const float* __restrict__ xyz,
                                                  float* __restrict__ out_xyz) {
    __shared__ float sx[N_*3];       // 48 KB xyz copy
    __shared__ float sout[K_*3];     // 12 KB selected centroids
    __shared__ float wv[2][4];
    __shared__ int   wi[2][4];
    const int b = blockIdx.x, t = threadIdx.x;
    const int l = t & 63, w = t >> 6;
    const float* xb = xyz + b * (N_ * 3);
    for (int e = t; e < N_*3; e += 256) sx[e] = xb[e];
    __syncthreads();
    float x0[16], y0[16], z0[16], dist[16];
    #pragma unroll
    for (int j = 0; j < 16; ++j) {
        int p = t * 16 + j;
        x0[j] = sx[p*3+0]; y0[j] = sx[p*3+1]; z0[j] = sx[p*3+2];
        dist[j] = 1e10f;
    }
    int far = 0;
    for (int s = 0; s < K_; ++s) {
        const float cx = sx[far*3+0], cy = sx[far*3+1], cz = sx[far*3+2];
        if (t == 0) {
            sout[s*3+0] = cx; sout[s*3+1] = cy; sout[s*3+2] = cz;
        }
        float v = -1.f; int ib = 0;
        {
            #pragma clang fp contract(fast)
            #pragma unroll
            for (int j = 0; j < 16; ++j) {
                float dx = x0[j]-cx, dy = y0[j]-cy, dz = z0[j]-cz;
                float dd = dx*dx + dy*dy + dz*dz;
                dd = fminf(dist[j], dd);
                dist[j] = dd;
                if (dd > v) { v = dd; ib = t*16 + j; }   // ascending j: first max
            }
        }
        float vr = v;
        wave_reduce_maxval(vr);
        const float m = __int_as_float(__builtin_amdgcn_readlane(__float_as_int(vr), 63));
        unsigned long long mk = __ballot(v == m);
        const int ln  = __ffsll((unsigned long long)mk) - 1;   // lowest tied lane
        const int wib = __builtin_amdgcn_readlane(ib, ln);
        const int pb = s & 1;
        if (l == 0) { wv[pb][w] = m; wi[pb][w] = wib; }
        __syncthreads();                   // only barrier per step
        float bv = wv[pb][0]; int bi = wi[pb][0];
        #pragma unroll
        for (int ww = 1; ww < 4; ++ww) {
            float ov = wv[pb][ww];
            if (ov > bv) { bv = ov; bi = wi[pb][ww]; }   // waves ascend idx
        }
        far = bi & 4095;
    }
    __syncthreads();                       // sout complete
    for (int e = t; e < K_*3; e += 256) out_xyz[b*K_*3 + e] = sout[e];
}

// ---------------------------------------------------------------- kNN ------
// Poison-select (r8-verified, ~-30 us vs threshold-rescan). r9: staging
// vectorized — 3 float4 loads deinterleave to 4 points (load count /4).
// r6: knn is VALU-issue-bound — shrink instructions, don't add waves.
__global__ __launch_bounds__(256) void knn_kernel(const float* __restrict__ xyz,
                                                  const float* __restrict__ newxyz) {
    __shared__ float px[N_], py[N_], pz[N_];
    const int b = blockIdx.y, t = threadIdx.x;
    const int l = t & 63, w = t >> 6;
    const int k = blockIdx.x * 4 + w;
    const int m = b*K_ + k;
    const float* xb = xyz + b * (N_ * 3);
    #pragma unroll
    for (int kk = 0; kk < 4; ++kk) {
        const int p0 = (t + kk*256) * 4;                 // 4 points/iter
        const float4* s = (const float4*)(xb + (size_t)p0*3);
        float4 a = s[0], bq = s[1], c = s[2];
        px[p0+0]=a.x;  py[p0+0]=a.y;  pz[p0+0]=a.z;
        px[p0+1]=a.w;  py[p0+1]=bq.x; pz[p0+1]=bq.y;
        px[p0+2]=bq.z; py[p0+2]=bq.w; pz[p0+2]=c.x;
        px[p0+3]=c.y;  py[p0+3]=c.z;  pz[p0+3]=c.w;
    }
    __syncthreads();
    const float cx = newxyz[m*3+0];
    const float cy = newxyz[m*3+1];
    const float cz = newxyz[m*3+2];
    float d[64];
    {
        #pragma clang fp contract(off)
        float sn = cx*cx; sn = sn + cy*cy; sn = sn + cz*cz;
        #pragma unroll
        for (int j = 0; j < 64; ++j) {
            int p = j*64 + l;
            float X = px[p], Y = py[p], Z = pz[p];
            float sp = X*X; sp = sp + Y*Y; sp = sp + Z*Z;
            float dt = cx*X; dt = dt + cy*Y; dt = dt + cz*Z;
            float t1 = sn + sp;
            d[j] = t1 - 2.0f*dt;
        }
    }
    for (int r = 0; r < NN_; ++r) {
        float bv = 1e38f; int bi = 0x7fffffff;
        #pragma unroll
        for (int j = 0; j < 64; ++j) {
            int p = j*64 + l;
            bool lt = (d[j] < bv) || (d[j] == bv && p < bi);
            if (lt) { bv = d[j]; bi = p; }
        }
        wave_reduce_min(bv, bi);
        const int win = __builtin_amdgcn_readlane(bi, 63);
        if (l == 0) g_knn[m*NN_ + r] = (u16)(win & 4095);
        #pragma unroll
        for (int j = 0; j < 64; ++j) {
            int p = j*64 + l;
            d[j] = (p == win) ? 1e38f : d[j];     // poison winner
        }
    }
}

// ------------------------------------------------- GEMM1 + stats + h1 ------
// r9 staging rewrite: Xs layout [points 0-63 | xyz 64-66 | zero 67] matches
// the permuted g_W1T, so points stage as 4 threads/row x 4 float4 loads +
// b128 LDS writes (was 17 iters of div68/mod68/scalar). GEMM unchanged
// (q-sum is permutation-invariant).
__global__ __launch_bounds__(256) void stats1_kernel(
        const float* __restrict__ xyz, const float* __restrict__ points,
        const float* __restrict__ newxyz, const float* __restrict__ b1) {
    __shared__ union {
        float Xs[64][68];
        struct { float ps[16][128], pq[16][128]; } c;
    } u;
    __shared__ float cen[4][3];
    __shared__ int rowp[64];
    const int t = threadIdx.x;
    const int blk = blockIdx.x;
    const int b = blk >> 8;
    const int g0 = blk * 64;
    if (t < 64)  rowp[t] = ((int)g_knn[g0 + t]) & 4095;
    if (t < 12)  cen[t/3][t%3] = newxyz[(blk*4 + t/3)*3 + (t%3)];
    __syncthreads();
    {   // points -> Xs[r][0..63]: 4 threads per row, float4 all the way
        const int r = t >> 2, q = t & 3;
        const int p = rowp[r];
        const float* src = points + ((size_t)(b*N_ + p))*64 + q*16;
        float4 v0 = *(const float4*)(src + 0);
        float4 v1 = *(const float4*)(src + 4);
        float4 v2 = *(const float4*)(src + 8);
        float4 v3 = *(const float4*)(src + 12);
        *(float4*)&u.Xs[r][q*16 + 0]  = v0;
        *(float4*)&u.Xs[r][q*16 + 4]  = v1;
        *(float4*)&u.Xs[r][q*16 + 8]  = v2;
        *(float4*)&u.Xs[r][q*16 + 12] = v3;
    }
    if (t < 64) {   // xyz -> Xs[r][64..66], col 67 zero
        const int p = rowp[t];
        const float* s = xyz + ((size_t)(b*N_ + p))*3;
        u.Xs[t][64] = s[0] - cen[t >> 4][0];
        u.Xs[t][65] = s[1] - cen[t >> 4][1];
        u.Xs[t][66] = s[2] - cen[t >> 4][2];
        u.Xs[t][67] = 0.f;
    }
    __syncthreads();
    const int rg = t >> 4, cg = t & 15;
    const int r0 = rg * 4;
    float acc[4][8];
    #pragma unroll
    for (int j = 0; j < 4; ++j)
        #pragma unroll
        for (int i = 0; i < 8; ++i) acc[j][i] = 0.f;
    for (int q4 = 0; q4 < 17; ++q4) {
        float4 xv[4];
        #pragma unroll
        for (int j = 0; j < 4; ++j) xv[j] = *(const float4*)&u.Xs[r0 + j][q4*4];
        #pragma unroll
        for (int i = 0; i < 8; ++i) {
            int o = cg + 16*i;
            float w0 = g_W1T[(q4*4+0)*128 + o];
            float w1 = g_W1T[(q4*4+1)*128 + o];
            float w2 = g_W1T[(q4*4+2)*128 + o];
            float w3 = g_W1T[(q4*4+3)*128 + o];
            #pragma unroll
            for (int j = 0; j < 4; ++j) {
                float a = acc[j][i];
                a = a + xv[j].x*w0; a = a + xv[j].y*w1;
                a = a + xv[j].z*w2; a = a + xv[j].w*w3;
                acc[j][i] = a;
            }
        }
    }
    __syncthreads();   // Xs reads done -> union reusable
    #pragma unroll
    for (int i = 0; i < 8; ++i) {
        int o = cg + 16*i;
        float bias = b1[o];
        float s = 0.f, sq = 0.f;
        #pragma unroll
        for (int j = 0; j < 4; ++j) {
            float v = acc[j][i] + bias;
            g_h1[(size_t)(g0 + r0 + j)*128 + o] = v;
            s += v; sq += v*v;
        }
        u.c.ps[rg][o] = s; u.c.pq[rg][o] = sq;
    }
    __syncthreads();
    if (t < 128) {
        float ts = 0.f, tq = 0.f;
        #pragma unroll
        for (int g = 0; g < 16; ++g) { ts += u.c.ps[g][t]; tq += u.c.pq[g][t]; }
        const int slot = (blk & 7) * 256;
        atomicAdd(&g_statsA[slot + t], ts);
        atomicAdd(&g_statsA[slot + 128 + t], tq);
    }
}

// ------------------------------------------------ BN1+ReLU + GEMM2 ---------
// r8 retile: 128 rows/block (1024 blocks), 8 rows/thread (proven -15 us).
__global__ __launch_bounds__(256) void gemm2_kernel(
        const float* __restrict__ b2, const float* __restrict__ g1,
        const float* __restrict__ be1) {
    __shared__ float mn1[128], sc1[128], bb1[128];
    __shared__ union {
        float h1s[128][132];
        struct { float ps[16][128], pq[16][128], pm[16][128]; } c;
    } u;
    const int t = threadIdx.x;
    const int blk = blockIdx.x;
    const int g0 = blk * 128;
    if (t < 128) {
        float sum = 0.f, sq = 0.f;
        #pragma unroll
        for (int s = 0; s < 8; ++s) {
            sum += g_statsA[s*256 + t];
            sq  += g_statsA[s*256 + 128 + t];
        }
        float mean = sum * (1.f / BN_N);
        float var  = sq * (1.f / BN_N) - mean*mean;
        mn1[t] = mean; sc1[t] = (1.f / sqrtf(var + 1e-5f)) * g1[t];
        bb1[t] = be1[t];
    }
    __syncthreads();
    for (int e = t*4; e < 128*128; e += 1024) {
        float4 hv = *(const float4*)&g_h1[(size_t)g0*128 + e];
        int r = e >> 7, c = e & 127;
        u.h1s[r][c+0] = fmaxf((hv.x - mn1[c+0])*sc1[c+0] + bb1[c+0], 0.f);
        u.h1s[r][c+1] = fmaxf((hv.y - mn1[c+1])*sc1[c+1] + bb1[c+1], 0.f);
        u.h1s[r][c+2] = fmaxf((hv.z - mn1[c+2])*sc1[c+2] + bb1[c+2], 0.f);
        u.h1s[r][c+3] = fmaxf((hv.w - mn1[c+3])*sc1[c+3] + bb1[c+3], 0.f);
    }
    __syncthreads();
    const int rg = t >> 4, cg = t & 15;
    const int r0 = rg * 8;
    float acc2[8][8];
    #pragma unroll
    for (int j = 0; j < 8; ++j)
        #pragma unroll
        for (int i = 0; i < 8; ++i) acc2[j][i] = 0.f;
    for (int q4 = 0; q4 < 32; ++q4) {
        float4 xv[8];
        #pragma unroll
        for (int j = 0; j < 8; ++j) xv[j] = *(const float4*)&u.h1s[r0 + j][q4*4];
        #pragma unroll
        for (int i = 0; i < 8; ++i) {
            int o = cg + 16*i;
            float w0 = g_W2T[(q4*4+0)*128 + o];
            float w1 = g_W2T[(q4*4+1)*128 + o];
            float w2 = g_W2T[(q4*4+2)*128 + o];
            float w3 = g_W2T[(q4*4+3)*128 + o];
            #pragma unroll
            for (int j = 0; j < 8; ++j) {
                float a = acc2[j][i];
                a = a + xv[j].x*w0; a = a + xv[j].y*w1;
                a = a + xv[j].z*w2; a = a + xv[j].w*w3;
                acc2[j][i] = a;
            }
        }
    }
    __syncthreads();   // h1s reads done -> union reusable
    #pragma unroll
    for (int i = 0; i < 8; ++i) {
        int o = cg + 16*i;
        float bias = b2[o];
        float s = 0.f, sq = 0.f, mx = -1e38f;
        #pragma unroll
        for (int j = 0; j < 8; ++j) {
            float v = acc2[j][i] + bias;
            s += v; sq += v*v; mx = fmaxf(mx, v);
        }
        u.c.ps[rg][o] = s; u.c.pq[rg][o] = sq; u.c.pm[rg][o] = mx;
    }
    __syncthreads();
    if (t < 128) {
        float ts = 0.f, tq = 0.f;
        #pragma unroll
        for (int g = 0; g < 16; ++g) { ts += u.c.ps[g][t]; tq += u.c.pq[g][t]; }
        const int slot = (blk & 7) * 256;
        atomicAdd(&g_statsB[slot + t], ts);
        atomicAdd(&g_statsB[slot + 128 + t], tq);
    }
    {
        // max-pool: 128 rows = 8 output m-rows (16 input rows each);
        // pm[rg] covers rows rg*8..rg*8+7 -> m-row gm uses rg = 2gm, 2gm+1.
        const int o = t & 127, gg = t >> 7;          // gg in {0,1}
        #pragma unroll
        for (int h = 0; h < 4; ++h) {
            const int gm = h*2 + gg;                 // 0..7
            float mx = fmaxf(u.c.pm[gm*2 + 0][o], u.c.pm[gm*2 + 1][o]);
            g_m2[(blk*8 + gm)*128 + o] = mx;
        }
    }
}

// ------------------------------------------------------------- finalize ----
__global__ __launch_bounds__(256) void final_kernel(
        const float* __restrict__ g2, const float* __restrict__ be2,
        float* __restrict__ outp) {
    __shared__ float mn[128], sc[128], bb[128];
    const int t = threadIdx.x;
    if (t < 128) {
        float sum = 0.f, sq = 0.f;
        #pragma unroll
        for (int s = 0; s < 8; ++s) {
            sum += g_statsB[s*256 + t];
            sq  += g_statsB[s*256 + 128 + t];
        }
        float mean = sum * (1.f / BN_N);
        float var  = sq * (1.f / BN_N) - mean*mean;
        float inv  = 1.f / sqrtf(var + 1e-5f);
        mn[t] = mean; sc[t] = inv * g2[t]; bb[t] = be2[t];
    }
    __syncthreads();
    const int m = blockIdx.x*2 + (t >> 7);
    const int c = t & 127;
    float v = (g_m2[m*128 + c] - mn[c]) * sc[c] + bb[c];
    v = fmaxf(v, 0.f);
    outp[m*C2_ + c] = v;
}

// -------------------------------------------------------------- launch -----
extern "C" void kernel_launch(void* const* d_in, const int* in_sizes, int n_in,
                              void* d_out, int out_size, void* d_ws, size_t ws_size,
                              hipStream_t stream) {
    const float* xyz    = (const float*)d_in[0];
    const float* points = (const float*)d_in[1];
    const float* W1     = (const float*)d_in[2];
    const float* b1     = (const float*)d_in[3];
    const float* g1     = (const float*)d_in[4];
    const float* be1    = (const float*)d_in[5];
    const float* W2     = (const float*)d_in[6];
    const float* b2     = (const float*)d_in[7];
    const float* g2     = (const float*)d_in[8];
    const float* be2    = (const float*)d_in[9];

    float* out_xyz = (float*)d_out;
    float* out_pts = (float*)d_out + B_*K_*3;

    (void)d_ws; (void)ws_size;

    transpose_w_kernel<<<64, 256, 0, stream>>>(W1, W2);   // + zeroes stats
    fps_kernel<<<B_, 256, 0, stream>>>(xyz, out_xyz);
    knn_kernel<<<dim3(256, B_), 256, 0, stream>>>(xyz, out_xyz);
    stats1_kernel<<<NBLK, 256, 0, stream>>>(xyz, points, out_xyz, b1);
    gemm2_kernel<<<NBLK2, 256, 0, stream>>>(b2, g1, be1);
    final_kernel<<<B_*K_/2, 256, 0, stream>>>(g2, be2, out_pts);
}

// Round 10
// 1000.124 us; speedup vs baseline: 1.7982x; 1.0030x over previous
//
#include <hip/hip_runtime.h>

#define B_ 8
#define N_ 4096
#define K_ 1024
#define NN_ 16
#define C1_ 128
#define C2_ 128
#define CIN_ 67
#define NROWS (B_*K_*NN_)   // 131072
#define NBLK  (NROWS/64)    // 2048 stats1 tiles
#define NBLK2 (NROWS/128)   // 1024 gemm2 tiles (128-row retile)
#define BN_N 131072.0f

typedef unsigned short u16;
typedef unsigned long long u64;

__device__ u16   g_knn[NROWS];
// BN accumulators, 8-way slot-spread (r18: 1M atomics on 256 addresses cost
// ~150 us of L2 same-address serialization; slot = blk&7 cuts it 8x).
__device__ float g_statsA[8*256];               // BN1 sum/sumsq per slot
__device__ float g_statsB[8*256];               // BN2 sum/sumsq per slot
__device__ float g_m2[B_*K_*C2_];
// W1^T PERMUTED row order: q<64 -> points channel 3+q; q 64..66 -> xyz
// channel q-64; q=67 -> 0. Matches stats1's Xs layout (points 0-63,
// xyz 64-66, zero 67) so staging is float4/b128 aligned.
__device__ float g_W1T[68*128];
__device__ float g_W2T[128*128];                // W2^T [q][o]
__device__ __align__(16) float g_h1[(size_t)NROWS*128];   // pre-BN1 h1 (64 MB)

// --------------------------------------------------- DPP wave reduction ----
// Value-only max reduce-to-lane-63 (12 inst). Index resolved via ballot +
// ffs + readlane — exact for fps (blocked ascending per-lane index ranges).
template<int CTRL>
static __device__ __forceinline__ void dpp_maxv_step(float& v) {
    int vi = __float_as_int(v);
    int ov = __builtin_amdgcn_update_dpp(vi, vi, CTRL, 0xf, 0xf, false);
    v = fmaxf(v, __int_as_float(ov));
}
static __device__ __forceinline__ void wave_reduce_maxval(float& v) {
    dpp_maxv_step<0x111>(v);
    dpp_maxv_step<0x112>(v);
    dpp_maxv_step<0x114>(v);
    dpp_maxv_step<0x118>(v);
    dpp_maxv_step<0x142>(v);
    dpp_maxv_step<0x143>(v);   // lane 63 holds max
}
// kNN keeps the lexicographic pair reduce (its indices are interleaved).
template<int CTRL>
static __device__ __forceinline__ void dpp_min_step(float& v, int& ib) {
    int vi = __float_as_int(v);
    int ov = __builtin_amdgcn_update_dpp(vi, vi, CTRL, 0xf, 0xf, false);
    int oi = __builtin_amdgcn_update_dpp(ib, ib, CTRL, 0xf, 0xf, false);
    float of = __int_as_float(ov);
    if (of < v || (of == v && oi < ib)) { v = of; ib = oi; }
}
static __device__ __forceinline__ void wave_reduce_min(float& v, int& ib) {
    dpp_min_step<0x111>(v, ib);
    dpp_min_step<0x112>(v, ib);
    dpp_min_step<0x114>(v, ib);
    dpp_min_step<0x118>(v, ib);
    dpp_min_step<0x142>(v, ib);
    dpp_min_step<0x143>(v, ib);
}

// ------------------------------------- weight transpose + stats zeroing ----
__global__ void transpose_w_kernel(const float* __restrict__ W1,
                                   const float* __restrict__ W2) {
    int t = blockIdx.x * 256 + threadIdx.x;
    if (t < 8*256) { g_statsA[t] = 0.f; g_statsB[t] = 0.f; }
    if (t < 68*128) {
        int q = t >> 7, o = t & 127;
        float v;
        if (q < 64)      v = W1[o*CIN_ + 3 + q];      // points channels
        else if (q < 67) v = W1[o*CIN_ + (q - 64)];   // xyz channels
        else             v = 0.f;
        g_W1T[t] = v;
    }
    if (t < 128*128) {
        int q = t >> 7, o = t & 127;
        g_W2T[t] = W2[o*C1_ + q];
    }
}

// ---------------------------------------------------------------- FPS ------
// v9 structure (609 us proven) + r10 tail: cross-wave select via ONE packed
// u64 LDS atomicMax per wave instead of {2 stores, 8 reads, 8-way chain}.
// pack = (float_bits(m)<<32) | (4095 - wib): m>=0 so float bits are
// monotonic; on equal m, larger low word = SMALLER index wins = jnp.argmax
// first-max tie-break (identical to the previous wave-ascending scan).
// 4-slot rotation: slot[(s+2)&3] zeroed pre-barrier at step s — its last
// reader finished before barrier s-1, next writer starts after barrier s.
// Dist loop / DPP / ballot / staging / sout all byte-identical to v9.
__global__ __launch_bounds__(256) void fps_kernel(const float* __restrict__ xyz,
                                                  float* __restrict__ out_xyz) {
    __shared__ float sx[N_*3];       // 48 KB xyz copy
    __shared__ float sout[K_*3];     // 12 KB selected centroids
    __shared__ u64   slot[4];
    const int b = blockIdx.x, t = threadIdx.x;
    const int l = t & 63, w = t >> 6;
    (void)w;
    const float* xb = xyz + b * (N_ * 3);
    for (int e = t; e < N_*3; e += 256) sx[e] = xb[e];
    if (t < 4) slot[t] = 0ull;
    __syncthreads();
    float x0[16], y0[16], z0[16], dist[16];
    #pragma unroll
    for (int j = 0; j < 16; ++j) {
        int p = t * 16 + j;
        x0[j] = sx[p*3+0]; y0[j] = sx[p*3+1]; z0[j] = sx[p*3+2];
        dist[j] = 1e10f;
    }
    int far = 0;
    for (int s = 0; s < K_; ++s) {
        const float cx = sx[far*3+0], cy = sx[far*3+1], cz = sx[far*3+2];
        if (t == 0) {
            sout[s*3+0] = cx; sout[s*3+1] = cy; sout[s*3+2] = cz;
        }
        float v = -1.f; int ib = 0;
        {
            #pragma clang fp contract(fast)
            #pragma unroll
            for (int j = 0; j < 16; ++j) {
                float dx = x0[j]-cx, dy = y0[j]-cy, dz = z0[j]-cz;
                float dd = dx*dx + dy*dy + dz*dz;
                dd = fminf(dist[j], dd);
                dist[j] = dd;
                if (dd > v) { v = dd; ib = t*16 + j; }   // ascending j: first max
            }
        }
        float vr = v;
        wave_reduce_maxval(vr);
        const float m = __int_as_float(__builtin_amdgcn_readlane(__float_as_int(vr), 63));
        unsigned long long mk = __ballot(v == m);
        const int ln  = __ffsll((unsigned long long)mk) - 1;   // lowest tied lane
        const int wib = __builtin_amdgcn_readlane(ib, ln);
        if (l == 0) {
            u64 pk = ((u64)(unsigned)__float_as_int(m) << 32) | (unsigned)(4095 - wib);
            atomicMax(&slot[s & 3], pk);
        }
        if (t == 0) slot[(s + 2) & 3] = 0ull;   // safe: see rotation proof
        __syncthreads();                   // only barrier per step
        u64 pk = slot[s & 3];
        far = 4095 - ((unsigned)pk & 4095);
    }
    __syncthreads();                       // sout complete
    for (int e = t; e < K_*3; e += 256) out_xyz[b*K_*3 + e] = sout[e];
}

// ---------------------------------------------------------------- kNN ------
// Poison-select (r8-verified, ~-30 us vs threshold-rescan). r9: staging
// vectorized — 3 float4 loads deinterleave to 4 points (load count /4).
// r6: knn is VALU-issue-bound — shrink instructions, don't add waves.
__global__ __launch_bounds__(256) void knn_kernel(const float* __restrict__ xyz,
                                                  const float* __restrict__ newxyz) {
    __shared__ float px[N_], py[N_], pz[N_];
    const int b = blockIdx.y, t = threadIdx.x;
    const int l = t & 63, w = t >> 6;
    const int k = blockIdx.x * 4 + w;
    const int m = b*K_ + k;
    const float* xb = xyz + b * (N_ * 3);
    #pragma unroll
    for (int kk = 0; kk < 4; ++kk) {
        const int p0 = (t + kk*256) * 4;                 // 4 points/iter
        const float4* s = (const float4*)(xb + (size_t)p0*3);
        float4 a = s[0], bq = s[1], c = s[2];
        px[p0+0]=a.x;  py[p0+0]=a.y;  pz[p0+0]=a.z;
        px[p0+1]=a.w;  py[p0+1]=bq.x; pz[p0+1]=bq.y;
        px[p0+2]=bq.z; py[p0+2]=bq.w; pz[p0+2]=c.x;
        px[p0+3]=c.y;  py[p0+3]=c.z;  pz[p0+3]=c.w;
    }
    __syncthreads();
    const float cx = newxyz[m*3+0];
    const float cy = newxyz[m*3+1];
    const float cz = newxyz[m*3+2];
    float d[64];
    {
        #pragma clang fp contract(off)
        float sn = cx*cx; sn = sn + cy*cy; sn = sn + cz*cz;
        #pragma unroll
        for (int j = 0; j < 64; ++j) {
            int p = j*64 + l;
            float X = px[p], Y = py[p], Z = pz[p];
            float sp = X*X; sp = sp + Y*Y; sp = sp + Z*Z;
            float dt = cx*X; dt = dt + cy*Y; dt = dt + cz*Z;
            float t1 = sn + sp;
            d[j] = t1 - 2.0f*dt;
        }
    }
    for (int r = 0; r < NN_; ++r) {
        float bv = 1e38f; int bi = 0x7fffffff;
        #pragma unroll
        for (int j = 0; j < 64; ++j) {
            int p = j*64 + l;
            bool lt = (d[j] < bv) || (d[j] == bv && p < bi);
            if (lt) { bv = d[j]; bi = p; }
        }
        wave_reduce_min(bv, bi);
        const int win = __builtin_amdgcn_readlane(bi, 63);
        if (l == 0) g_knn[m*NN_ + r] = (u16)(win & 4095);
        #pragma unroll
        for (int j = 0; j < 64; ++j) {
            int p = j*64 + l;
            d[j] = (p == win) ? 1e38f : d[j];     // poison winner
        }
    }
}

// ------------------------------------------------- GEMM1 + stats + h1 ------
// r9 staging: Xs layout [points 0-63 | xyz 64-66 | zero 67] matches the
// permuted g_W1T; points stage as 4 threads/row x 4 float4 loads.
__global__ __launch_bounds__(256) void stats1_kernel(
        const float* __restrict__ xyz, const float* __restrict__ points,
        const float* __restrict__ newxyz, const float* __restrict__ b1) {
    __shared__ union {
        float Xs[64][68];
        struct { float ps[16][128], pq[16][128]; } c;
    } u;
    __shared__ float cen[4][3];
    __shared__ int rowp[64];
    const int t = threadIdx.x;
    const int blk = blockIdx.x;
    const int b = blk >> 8;
    const int g0 = blk * 64;
    if (t < 64)  rowp[t] = ((int)g_knn[g0 + t]) & 4095;
    if (t < 12)  cen[t/3][t%3] = newxyz[(blk*4 + t/3)*3 + (t%3)];
    __syncthreads();
    {   // points -> Xs[r][0..63]: 4 threads per row, float4 all the way
        const int r = t >> 2, q = t & 3;
        const int p = rowp[r];
        const float* src = points + ((size_t)(b*N_ + p))*64 + q*16;
        float4 v0 = *(const float4*)(src + 0);
        float4 v1 = *(const float4*)(src + 4);
        float4 v2 = *(const float4*)(src + 8);
        float4 v3 = *(const float4*)(src + 12);
        *(float4*)&u.Xs[r][q*16 + 0]  = v0;
        *(float4*)&u.Xs[r][q*16 + 4]  = v1;
        *(float4*)&u.Xs[r][q*16 + 8]  = v2;
        *(float4*)&u.Xs[r][q*16 + 12] = v3;
    }
    if (t < 64) {   // xyz -> Xs[r][64..66], col 67 zero
        const int p = rowp[t];
        const float* s = xyz + ((size_t)(b*N_ + p))*3;
        u.Xs[t][64] = s[0] - cen[t >> 4][0];
        u.Xs[t][65] = s[1] - cen[t >> 4][1];
        u.Xs[t][66] = s[2] - cen[t >> 4][2];
        u.Xs[t][67] = 0.f;
    }
    __syncthreads();
    const int rg = t >> 4, cg = t & 15;
    const int r0 = rg * 4;
    float acc[4][8];
    #pragma unroll
    for (int j = 0; j < 4; ++j)
        #pragma unroll
        for (int i = 0; i < 8; ++i) acc[j][i] = 0.f;
    for (int q4 = 0; q4 < 17; ++q4) {
        float4 xv[4];
        #pragma unroll
        for (int j = 0; j < 4; ++j) xv[j] = *(const float4*)&u.Xs[r0 + j][q4*4];
        #pragma unroll
        for (int i = 0; i < 8; ++i) {
            int o = cg + 16*i;
            float w0 = g_W1T[(q4*4+0)*128 + o];
            float w1 = g_W1T[(q4*4+1)*128 + o];
            float w2 = g_W1T[(q4*4+2)*128 + o];
            float w3 = g_W1T[(q4*4+3)*128 + o];
            #pragma unroll
            for (int j = 0; j < 4; ++j) {
                float a = acc[j][i];
                a = a + xv[j].x*w0; a = a + xv[j].y*w1;
                a = a + xv[j].z*w2; a = a + xv[j].w*w3;
                acc[j][i] = a;
            }
        }
    }
    __syncthreads();   // Xs reads done -> union reusable
    #pragma unroll
    for (int i = 0; i < 8; ++i) {
        int o = cg + 16*i;
        float bias = b1[o];
        float s = 0.f, sq = 0.f;
        #pragma unroll
        for (int j = 0; j < 4; ++j) {
            float v = acc[j][i] + bias;
            g_h1[(size_t)(g0 + r0 + j)*128 + o] = v;
            s += v; sq += v*v;
        }
        u.c.ps[rg][o] = s; u.c.pq[rg][o] = sq;
    }
    __syncthreads();
    if (t < 128) {
        float ts = 0.f, tq = 0.f;
        #pragma unroll
        for (int g = 0; g < 16; ++g) { ts += u.c.ps[g][t]; tq += u.c.pq[g][t]; }
        const int slot = (blk & 7) * 256;
        atomicAdd(&g_statsA[slot + t], ts);
        atomicAdd(&g_statsA[slot + 128 + t], tq);
    }
}

// ------------------------------------------------ BN1+ReLU + GEMM2 ---------
// r8 retile: 128 rows/block (1024 blocks), 8 rows/thread (proven -15 us).
__global__ __launch_bounds__(256) void gemm2_kernel(
        const float* __restrict__ b2, const float* __restrict__ g1,
        const float* __restrict__ be1) {
    __shared__ float mn1[128], sc1[128], bb1[128];
    __shared__ union {
        float h1s[128][132];
        struct { float ps[16][128], pq[16][128], pm[16][128]; } c;
    } u;
    const int t = threadIdx.x;
    const int blk = blockIdx.x;
    const int g0 = blk * 128;
    if (t < 128) {
        float sum = 0.f, sq = 0.f;
        #pragma unroll
        for (int s = 0; s < 8; ++s) {
            sum += g_statsA[s*256 + t];
            sq  += g_statsA[s*256 + 128 + t];
        }
        float mean = sum * (1.f / BN_N);
        float var  = sq * (1.f / BN_N) - mean*mean;
        mn1[t] = mean; sc1[t] = (1.f / sqrtf(var + 1e-5f)) * g1[t];
        bb1[t] = be1[t];
    }
    __syncthreads();
    for (int e = t*4; e < 128*128; e += 1024) {
        float4 hv = *(const float4*)&g_h1[(size_t)g0*128 + e];
        int r = e >> 7, c = e & 127;
        u.h1s[r][c+0] = fmaxf((hv.x - mn1[c+0])*sc1[c+0] + bb1[c+0], 0.f);
        u.h1s[r][c+1] = fmaxf((hv.y - mn1[c+1])*sc1[c+1] + bb1[c+1], 0.f);
        u.h1s[r][c+2] = fmaxf((hv.z - mn1[c+2])*sc1[c+2] + bb1[c+2], 0.f);
        u.h1s[r][c+3] = fmaxf((hv.w - mn1[c+3])*sc1[c+3] + bb1[c+3], 0.f);
    }
    __syncthreads();
    const int rg = t >> 4, cg = t & 15;
    const int r0 = rg * 8;
    float acc2[8][8];
    #pragma unroll
    for (int j = 0; j < 8; ++j)
        #pragma unroll
        for (int i = 0; i < 8; ++i) acc2[j][i] = 0.f;
    for (int q4 = 0; q4 < 32; ++q4) {
        float4 xv[8];
        #pragma unroll
        for (int j = 0; j < 8; ++j) xv[j] = *(const float4*)&u.h1s[r0 + j][q4*4];
        #pragma unroll
        for (int i = 0; i < 8; ++i) {
            int o = cg + 16*i;
            float w0 = g_W2T[(q4*4+0)*128 + o];
            float w1 = g_W2T[(q4*4+1)*128 + o];
            float w2 = g_W2T[(q4*4+2)*128 + o];
            float w3 = g_W2T[(q4*4+3)*128 + o];
            #pragma unroll
            for (int j = 0; j < 8; ++j) {
                float a = acc2[j][i];
                a = a + xv[j].x*w0; a = a + xv[j].y*w1;
                a = a + xv[j].z*w2; a = a + xv[j].w*w3;
                acc2[j][i] = a;
            }
        }
    }
    __syncthreads();   // h1s reads done -> union reusable
    #pragma unroll
    for (int i = 0; i < 8; ++i) {
        int o = cg + 16*i;
        float bias = b2[o];
        float s = 0.f, sq = 0.f, mx = -1e38f;
        #pragma unroll
        for (int j = 0; j < 8; ++j) {
            float v = acc2[j][i] + bias;
            s += v; sq += v*v; mx = fmaxf(mx, v);
        }
        u.c.ps[rg][o] = s; u.c.pq[rg][o] = sq; u.c.pm[rg][o] = mx;
    }
    __syncthreads();
    if (t < 128) {
        float ts = 0.f, tq = 0.f;
        #pragma unroll
        for (int g = 0; g < 16; ++g) { ts += u.c.ps[g][t]; tq += u.c.pq[g][t]; }
        const int slot = (blk & 7) * 256;
        atomicAdd(&g_statsB[slot + t], ts);
        atomicAdd(&g_statsB[slot + 128 + t], tq);
    }
    {
        // max-pool: 128 rows = 8 output m-rows (16 input rows each);
        // pm[rg] covers rows rg*8..rg*8+7 -> m-row gm uses rg = 2gm, 2gm+1.
        const int o = t & 127, gg = t >> 7;          // gg in {0,1}
        #pragma unroll
        for (int h = 0; h < 4; ++h) {
            const int gm = h*2 + gg;                 // 0..7
            float mx = fmaxf(u.c.pm[gm*2 + 0][o], u.c.pm[gm*2 + 1][o]);
            g_m2[(blk*8 + gm)*128 + o] = mx;
        }
    }
}

// ------------------------------------------------------------- finalize ----
__global__ __launch_bounds__(256) void final_kernel(
        const float* __restrict__ g2, const float* __restrict__ be2,
        float* __restrict__ outp) {
    __shared__ float mn[128], sc[128], bb[128];
    const int t = threadIdx.x;
    if (t < 128) {
        float sum = 0.f, sq = 0.f;
        #pragma unroll
        for (int s = 0; s < 8; ++s) {
            sum += g_statsB[s*256 + t];
            sq  += g_statsB[s*256 + 128 + t];
        }
        float mean = sum * (1.f / BN_N);
        float var  = sq * (1.f / BN_N) - mean*mean;
        float inv  = 1.f / sqrtf(var + 1e-5f);
        mn[t] = mean; sc[t] = inv * g2[t]; bb[t] = be2[t];
    }
    __syncthreads();
    const int m = blockIdx.x*2 + (t >> 7);
    const int c = t & 127;
    float v = (g_m2[m*128 + c] - mn[c]) * sc[c] + bb[c];
    v = fmaxf(v, 0.f);
    outp[m*C2_ + c] = v;
}

// -------------------------------------------------------------- launch -----
extern "C" void kernel_launch(void* const* d_in, const int* in_sizes, int n_in,
                              void* d_out, int out_size, void* d_ws, size_t ws_size,
                              hipStream_t stream) {
    const float* xyz    = (const float*)d_in[0];
    const float* points = (const float*)d_in[1];
    const float* W1     = (const float*)d_in[2];
    const float* b1     = (const float*)d_in[3];
    const float* g1     = (const float*)d_in[4];
    const float* be1    = (const float*)d_in[5];
    const float* W2     = (const float*)d_in[6];
    const float* b2     = (const float*)d_in[7];
    const float* g2     = (const float*)d_in[8];
    const float* be2    = (const float*)d_in[9];

    float* out_xyz = (float*)d_out;
    float* out_pts = (float*)d_out + B_*K_*3;

    (void)d_ws; (void)ws_size;

    transpose_w_kernel<<<64, 256, 0, stream>>>(W1, W2);   // + zeroes stats
    fps_kernel<<<B_, 256, 0, stream>>>(xyz, out_xyz);
    knn_kernel<<<dim3(256, B_), 256, 0, stream>>>(xyz, out_xyz);
    stats1_kernel<<<NBLK, 256, 0, stream>>>(xyz, points, out_xyz, b1);
    gemm2_kernel<<<NBLK2, 256, 0, stream>>>(b2, g1, be1);
    final_kernel<<<B_*K_/2, 256, 0, stream>>>(g2, be2, out_pts);
}